// Round 2
// baseline (284.112 us; speedup 1.0000x reference)
//
#include <hip/hip_runtime.h>
#include <math.h>

// MFA Woodbury log-likelihood:
//   per_comp[k,n] = c0_k + x_n.w_k - 0.5*(x_n^2).iD_k + 0.5*||G_k^T x_n - h_k||^2
//   out[n] = logsumexp_k per_comp[k,n]
// L_k = I + A^T diag(iD) A = C C^T (Cholesky), Winv = C^{-1}
// Gt_k (64x512) = Winv * AiD_k^T ;  h_k = Winv * (AiD^T mu)
// Main GEMM x(4096x512) @ Gt^T(512x8192) bf16 MFMA, XOR-swizzled LDS, fused SSQ.

#define KC 128
#define DF 512
#define LF 64
#define NN 4096

typedef __attribute__((ext_vector_type(8))) short short8;
typedef __attribute__((ext_vector_type(4))) float f32x4;

static __device__ __forceinline__ unsigned short bfr(float f) {
  union { float f; unsigned u; } v; v.f = f;
  return (unsigned short)((v.u + 0x7FFFu + ((v.u >> 16) & 1u)) >> 16);
}

static __device__ __forceinline__ void ldst16(void* lds, const void* g) {
  __builtin_amdgcn_global_load_lds((const __attribute__((address_space(1))) void*)g,
                                   (__attribute__((address_space(3))) void*)lds,
                                   16, 0, 0);
}

// ---------------- X: x -> bf16, x^2 -> bf16 ----------------
__global__ __launch_bounds__(256) void mfa_convert(const float* __restrict__ x,
                                                   unsigned short* __restrict__ xbf,
                                                   unsigned short* __restrict__ x2bf) {
  int idx = blockIdx.x * 256 + threadIdx.x;
  float4 v = reinterpret_cast<const float4*>(x)[idx];
  ushort4 a, b;
  a.x = bfr(v.x); a.y = bfr(v.y); a.z = bfr(v.z); a.w = bfr(v.w);
  b.x = bfr(v.x * v.x); b.y = bfr(v.y * v.y); b.z = bfr(v.z * v.z); b.w = bfr(v.w * v.w);
  reinterpret_cast<ushort4*>(xbf)[idx] = a;
  reinterpret_cast<ushort4*>(x2bf)[idx] = b;
}

// ---------------- S1: per-k stats (no A access) ----------------
__global__ __launch_bounds__(256) void mfa_stats(const float* __restrict__ MU,
                                                 const float* __restrict__ Dp,
                                                 const float* __restrict__ PI,
                                                 float* __restrict__ iDf,
                                                 unsigned short* __restrict__ iDbf,
                                                 unsigned short* __restrict__ wbf,
                                                 float* __restrict__ miDf,
                                                 float* __restrict__ c0a) {
  int k = blockIdx.x, tid = threadIdx.x;
  __shared__ float redA[256];
  __shared__ float redB[256];
  float slog = 0.f, smu2 = 0.f;
  for (int d = tid; d < DF; d += 256) {
    float Dv = Dp[k * DF + d];
    float id = 1.f / (Dv * Dv);
    iDf[k * DF + d] = id;
    iDbf[k * DF + d] = bfr(id);
    float mu = MU[k * DF + d];
    float wv = id * mu;
    wbf[k * DF + d] = bfr(wv);
    miDf[k * DF + d] = wv;
    slog += logf(id);
    smu2 += wv * mu;
  }
  redA[tid] = slog; redB[tid] = smu2;
  __syncthreads();
  for (int s = 128; s > 0; s >>= 1) {
    if (tid < s) { redA[tid] += redA[tid + s]; redB[tid] += redB[tid + s]; }
    __syncthreads();
  }
  if (tid == 0)
    c0a[k] = PI[k] - 0.5f * (DF * 1.8378770664093453f + redB[0] - redA[0]);
}

// ---------------- S2: Lp[h] = (A^T diag(iD) A) over half-d; m2 partial ----------------
__global__ __launch_bounds__(256) void mfa_lmat(const float* __restrict__ A,
                                                const float* __restrict__ iDf,
                                                const float* __restrict__ miDf,
                                                float* __restrict__ Lp,
                                                float* __restrict__ m2p) {
  int k = blockIdx.x, h = blockIdx.y, tid = threadIdx.x;
  __shared__ float As2[64][68];
  __shared__ float iDs2[64];
  __shared__ float miDs[64];
  __shared__ float red[256];
  int ti = tid >> 4, tj = tid & 15;
  float acc[4][4];
#pragma unroll
  for (int a = 0; a < 4; ++a)
#pragma unroll
    for (int b = 0; b < 4; ++b) acc[a][b] = 0.f;
  float m2acc = 0.f;
  int ii = tid & 63, dsub = tid >> 6;
  for (int dcc = 0; dcc < 4; ++dcc) {
    int dc = h * 4 + dcc;
    __syncthreads();
#pragma unroll
    for (int rr = 0; rr < 4; ++rr) {
      int d = rr * 16 + (tid >> 4);
      int c4 = (tid & 15) * 4;
      const float4 v = *reinterpret_cast<const float4*>(&A[((size_t)(k * DF + dc * 64 + d)) * LF + c4]);
      As2[d][c4] = v.x; As2[d][c4 + 1] = v.y; As2[d][c4 + 2] = v.z; As2[d][c4 + 3] = v.w;
    }
    if (tid < 64) { iDs2[tid] = iDf[k * DF + dc * 64 + tid]; miDs[tid] = miDf[k * DF + dc * 64 + tid]; }
    __syncthreads();
#pragma unroll 8
    for (int d = 0; d < 64; ++d) {
      float idv = iDs2[d];
      f32x4 ai = *reinterpret_cast<const f32x4*>(&As2[d][ti * 4]);
      f32x4 aj = *reinterpret_cast<const f32x4*>(&As2[d][tj * 4]);
      float a0 = ai[0] * idv, a1 = ai[1] * idv, a2 = ai[2] * idv, a3 = ai[3] * idv;
      acc[0][0] += a0 * aj[0]; acc[0][1] += a0 * aj[1]; acc[0][2] += a0 * aj[2]; acc[0][3] += a0 * aj[3];
      acc[1][0] += a1 * aj[0]; acc[1][1] += a1 * aj[1]; acc[1][2] += a1 * aj[2]; acc[1][3] += a1 * aj[3];
      acc[2][0] += a2 * aj[0]; acc[2][1] += a2 * aj[1]; acc[2][2] += a2 * aj[2]; acc[2][3] += a2 * aj[3];
      acc[3][0] += a3 * aj[0]; acc[3][1] += a3 * aj[1]; acc[3][2] += a3 * aj[2]; acc[3][3] += a3 * aj[3];
    }
#pragma unroll
    for (int dd = 0; dd < 16; ++dd) {
      int d = dsub * 16 + dd;
      m2acc += As2[d][ii] * miDs[d];
    }
  }
  float* Lk = Lp + ((size_t)h * KC + k) * 4096;
#pragma unroll
  for (int a = 0; a < 4; ++a)
#pragma unroll
    for (int b = 0; b < 4; ++b)
      Lk[(ti * 4 + a) * 64 + tj * 4 + b] = acc[a][b];
  red[tid] = m2acc;
  __syncthreads();
  if (tid < 64)
    m2p[((size_t)h * KC + k) * 64 + tid] = red[tid] + red[tid + 64] + red[tid + 128] + red[tid + 192];
}

// ---------------- S3: Cholesky + logdet + h + Winv = C^{-1} ----------------
__global__ __launch_bounds__(256) void mfa_chol(const float* __restrict__ Lp,
                                                const float* __restrict__ m2p,
                                                const float* __restrict__ c0a,
                                                float* __restrict__ Winv,
                                                float* __restrict__ hws,
                                                float* __restrict__ c0) {
  int k = blockIdx.x, tid = threadIdx.x;
  __shared__ float Cm[64 * 65];
  __shared__ float Wm[64 * 65];
  __shared__ float red[64];
  for (int idx = tid; idx < 4096; idx += 256) {
    int r = idx >> 6, c = idx & 63;
    float v = Lp[(size_t)k * 4096 + idx] + Lp[((size_t)KC + k) * 4096 + idx];
    Cm[r * 65 + c] = v + (r == c ? 1.f : 0.f);
  }
  __syncthreads();
  int tr = tid >> 4, tc = tid & 15;
  // Right-looking Cholesky: diag kept RAW (= C_jj^2), strict lower scaled.
  for (int j = 0; j < 64; ++j) {
    float v = Cm[j * 65 + j];
    float inv = 1.0f / sqrtf(v);
    if (tid < 64 && tid > j) Cm[tid * 65 + j] *= inv;
    __syncthreads();
#pragma unroll
    for (int a = 0; a < 4; ++a)
#pragma unroll
      for (int b = 0; b < 4; ++b) {
        int r = j + 1 + tr + 16 * a;
        int c = j + 1 + tc + 16 * b;
        if (r < 64 && c < 64)
          Cm[r * 65 + c] -= Cm[r * 65 + j] * Cm[c * 65 + j];
      }
    __syncthreads();
  }
  if (tid < 64) red[tid] = logf(Cm[tid * 65 + tid]);  // log(C_jj^2) sums to logdetL
  __syncthreads();
  if (tid == 0) {
    float s = 0.f;
    for (int q = 0; q < 64; ++q) s += red[q];
    c0[k] = c0a[k] - 0.5f * s;
  }
  // wave 0: h = C^{-1} m2 (wave-parallel fwd subst)
  if (tid < 64) {
    int l = tid;
    float m2v = m2p[k * 64 + l] + m2p[(KC + k) * 64 + l];
    float invdl = 1.0f / sqrtf(Cm[l * 65 + l]);
    float hl = 0.f;
    for (int r = 0; r < 64; ++r) {
      float contrib = (l < r) ? Cm[r * 65 + l] * hl : 0.f;
      contrib += __shfl_xor(contrib, 1, 64);
      contrib += __shfl_xor(contrib, 2, 64);
      contrib += __shfl_xor(contrib, 4, 64);
      contrib += __shfl_xor(contrib, 8, 64);
      contrib += __shfl_xor(contrib, 16, 64);
      contrib += __shfl_xor(contrib, 32, 64);
      if (l == r) hl = (m2v - contrib) * invdl;
    }
    hws[k * 64 + l] = hl;
  }
  // wave 1: Winv columns (thread-private: column j touched only by thread j)
  if (tid >= 64 && tid < 128) {
    int j = tid - 64;
    float invdj = 1.0f / sqrtf(Cm[j * 65 + j]);
    Wm[j * 65 + j] = invdj;
    for (int r = j + 1; r < 64; ++r) {
      float s = 0.f;
      for (int i = j; i < r; ++i) s += Cm[r * 65 + i] * Wm[i * 65 + j];
      Wm[r * 65 + j] = -s / sqrtf(Cm[r * 65 + r]);
    }
  }
  __syncthreads();
  for (int idx = tid; idx < 4096; idx += 256) {
    int r = idx >> 6, c = idx & 63;
    Winv[(size_t)k * 4096 + idx] = (c <= r) ? Wm[r * 65 + c] : 0.f;
  }
}

// ---------------- S4: Gt = Winv * AiD^T  (fp32, broadcast LDS) ----------------
__global__ __launch_bounds__(256) void mfa_gt(const float* __restrict__ A,
                                              const float* __restrict__ iDf,
                                              const float* __restrict__ Winv,
                                              unsigned short* __restrict__ Gt) {
  int k = blockIdx.x, dch = blockIdx.y, tid = threadIdx.x;
  __shared__ float Ws[64 * 65];
  __shared__ float As[64][132];  // [i][d_local], 128 d per block
  for (int idx = tid; idx < 4096; idx += 256)
    Ws[(idx >> 6) * 65 + (idx & 63)] = Winv[(size_t)k * 4096 + idx];
#pragma unroll
  for (int it = 0; it < 8; ++it) {
    int dloc = it * 16 + (tid >> 4);
    int d = dch * 128 + dloc;
    int i4 = (tid & 15) * 4;
    float4 v = *reinterpret_cast<const float4*>(&A[((size_t)(k * DF + d)) * LF + i4]);
    float idv = iDf[k * DF + d];
    As[i4][dloc] = v.x * idv; As[i4 + 1][dloc] = v.y * idv;
    As[i4 + 2][dloc] = v.z * idv; As[i4 + 3][dloc] = v.w * idv;
  }
  __syncthreads();
  int l = tid & 63, q = tid >> 6;  // wave q -> d quarter q*32
  float acc[32];
#pragma unroll
  for (int v = 0; v < 32; ++v) acc[v] = 0.f;
  for (int i = 0; i < 64; ++i) {
    float wv = Ws[l * 65 + i];
    const f32x4* ap = reinterpret_cast<const f32x4*>(&As[i][q * 32]);
#pragma unroll
    for (int v = 0; v < 8; ++v) {
      f32x4 a = ap[v];
      acc[v * 4 + 0] += wv * a[0]; acc[v * 4 + 1] += wv * a[1];
      acc[v * 4 + 2] += wv * a[2]; acc[v * 4 + 3] += wv * a[3];
    }
  }
  unsigned short tmp[32];
#pragma unroll
  for (int v = 0; v < 32; ++v) tmp[v] = bfr(acc[v]);
  uint4* dst = reinterpret_cast<uint4*>(&Gt[((size_t)(k * 64 + l)) * DF + dch * 128 + q * 32]);
#pragma unroll
  for (int u = 0; u < 4; ++u) {
    uint4 val;
    val.x = (unsigned)tmp[u * 8 + 0] | ((unsigned)tmp[u * 8 + 1] << 16);
    val.y = (unsigned)tmp[u * 8 + 2] | ((unsigned)tmp[u * 8 + 3] << 16);
    val.z = (unsigned)tmp[u * 8 + 4] | ((unsigned)tmp[u * 8 + 5] << 16);
    val.w = (unsigned)tmp[u * 8 + 6] | ((unsigned)tmp[u * 8 + 7] << 16);
    dst[u] = val;
  }
}

// ---------------- Q: r1 = c0 + x.w ; r2 = -0.5 * x^2.iD  (swizzled MFMA) ----------------
__global__ __launch_bounds__(256) void mfa_q1(const unsigned short* __restrict__ xbf,
                                              const unsigned short* __restrict__ x2bf,
                                              const unsigned short* __restrict__ wbf,
                                              const unsigned short* __restrict__ iDbf,
                                              const float* __restrict__ c0,
                                              float* __restrict__ r1,
                                              float* __restrict__ r2) {
  int nb = blockIdx.x * 128;
  int z = blockIdx.y;
  const unsigned short* Ap = z ? x2bf : xbf;
  const unsigned short* Bp = z ? iDbf : wbf;
  float* outp = z ? r2 : r1;
  int tid = threadIdx.x, lane = tid & 63, w = tid >> 6, wx = w & 1, wy = w >> 1;
  __shared__ unsigned short As[128 * 64];
  __shared__ unsigned short Bs[128 * 64];
  f32x4 acc[4][4];
  f32x4 zero = {0.f, 0.f, 0.f, 0.f};
#pragma unroll
  for (int mi = 0; mi < 4; ++mi)
#pragma unroll
    for (int nj = 0; nj < 4; ++nj) acc[mi][nj] = zero;
  const unsigned short* xg = Ap + (size_t)nb * DF;
  int lr = lane >> 3, lc = lane & 7;
  int gcs = (lc ^ lr) * 8;  // swizzled global column for this lane's LDS slot
  for (int kt = 0; kt < 8; ++kt) {
#pragma unroll
    for (int it = 0; it < 4; ++it) {
      int row = w * 8 + it * 32 + lr;
      ldst16(&As[(w * 8 + it * 32) * 64], xg + (size_t)row * DF + kt * 64 + gcs);
      ldst16(&Bs[(w * 8 + it * 32) * 64], Bp + (size_t)row * DF + kt * 64 + gcs);
    }
    __syncthreads();
#pragma unroll
    for (int kk = 0; kk < 2; ++kk) {
      int sw = ((kk * 4 + (lane >> 4)) ^ (lane & 7)) * 8;
      short8 av[4], bv[4];
#pragma unroll
      for (int mi = 0; mi < 4; ++mi)
        av[mi] = *reinterpret_cast<const short8*>(&As[(wy * 64 + mi * 16 + (lane & 15)) * 64 + sw]);
#pragma unroll
      for (int nj = 0; nj < 4; ++nj)
        bv[nj] = *reinterpret_cast<const short8*>(&Bs[(wx * 64 + nj * 16 + (lane & 15)) * 64 + sw]);
#pragma unroll
      for (int mi = 0; mi < 4; ++mi)
#pragma unroll
        for (int nj = 0; nj < 4; ++nj)
          acc[mi][nj] = __builtin_amdgcn_mfma_f32_16x16x32_bf16(av[mi], bv[nj], acc[mi][nj], 0, 0, 0);
    }
    __syncthreads();
  }
#pragma unroll
  for (int mi = 0; mi < 4; ++mi)
#pragma unroll
    for (int nj = 0; nj < 4; ++nj) {
      int ccol = wx * 64 + nj * 16 + (lane & 15);
      int nrow = nb + wy * 64 + mi * 16 + (lane >> 4) * 4;
      float4 o;
      if (z == 0) {
        float c = c0[ccol];
        o.x = acc[mi][nj][0] + c; o.y = acc[mi][nj][1] + c;
        o.z = acc[mi][nj][2] + c; o.w = acc[mi][nj][3] + c;
      } else {
        o.x = -0.5f * acc[mi][nj][0]; o.y = -0.5f * acc[mi][nj][1];
        o.z = -0.5f * acc[mi][nj][2]; o.w = -0.5f * acc[mi][nj][3];
      }
      *reinterpret_cast<float4*>(&outp[(size_t)ccol * NN + nrow]) = o;
    }
}

// ---------------- M: main GEMM + fused 0.5*||u-h||^2 + r1 + r2 ----------------
__global__ __launch_bounds__(256) void mfa_main(const unsigned short* __restrict__ xbf,
                                                const unsigned short* __restrict__ Gt,
                                                const float* __restrict__ hws,
                                                const float* __restrict__ r1,
                                                const float* __restrict__ r2,
                                                float* __restrict__ s2b) {
  int bx = blockIdx.x, by = blockIdx.y;
  int tid = threadIdx.x, lane = tid & 63, w = tid >> 6, wx = w & 1, wy = w >> 1;
  __shared__ unsigned short As[128 * 64];
  __shared__ unsigned short Bs[128 * 64];
  f32x4 acc[4][4];
  f32x4 zero = {0.f, 0.f, 0.f, 0.f};
#pragma unroll
  for (int mi = 0; mi < 4; ++mi)
#pragma unroll
    for (int nj = 0; nj < 4; ++nj) acc[mi][nj] = zero;
  int nbase = by * 128, cbase = bx * 128;
  const unsigned short* xg = xbf + (size_t)nbase * DF;
  const unsigned short* gg = Gt + (size_t)cbase * DF;
  int lr = lane >> 3, lc = lane & 7;
  int gcs = (lc ^ lr) * 8;
  for (int kt = 0; kt < 8; ++kt) {
#pragma unroll
    for (int it = 0; it < 4; ++it) {
      int row = w * 8 + it * 32 + lr;
      ldst16(&As[(w * 8 + it * 32) * 64], xg + (size_t)row * DF + kt * 64 + gcs);
      ldst16(&Bs[(w * 8 + it * 32) * 64], gg + (size_t)row * DF + kt * 64 + gcs);
    }
    __syncthreads();
#pragma unroll
    for (int kk = 0; kk < 2; ++kk) {
      int sw = ((kk * 4 + (lane >> 4)) ^ (lane & 7)) * 8;
      short8 av[4], bv[4];
#pragma unroll
      for (int mi = 0; mi < 4; ++mi)
        av[mi] = *reinterpret_cast<const short8*>(&As[(wy * 64 + mi * 16 + (lane & 15)) * 64 + sw]);
#pragma unroll
      for (int nj = 0; nj < 4; ++nj)
        bv[nj] = *reinterpret_cast<const short8*>(&Bs[(wx * 64 + nj * 16 + (lane & 15)) * 64 + sw]);
#pragma unroll
      for (int mi = 0; mi < 4; ++mi)
#pragma unroll
        for (int nj = 0; nj < 4; ++nj)
          acc[mi][nj] = __builtin_amdgcn_mfma_f32_16x16x32_bf16(av[mi], bv[nj], acc[mi][nj], 0, 0, 0);
    }
    __syncthreads();
  }
  // epilogue: per-wave component; sum (u-h)^2 over its 64 cols; add r1+r2
  int comp = bx * 2 + wx;
  float hv[4];
#pragma unroll
  for (int nj = 0; nj < 4; ++nj) hv[nj] = hws[comp * 64 + nj * 16 + (lane & 15)];
  int rbase = nbase + wy * 64;
#pragma unroll
  for (int mi = 0; mi < 4; ++mi) {
#pragma unroll
    for (int reg = 0; reg < 4; ++reg) {
      float s = 0.f;
#pragma unroll
      for (int nj = 0; nj < 4; ++nj) {
        float dlt = acc[mi][nj][reg] - hv[nj];
        s += dlt * dlt;
      }
      s += __shfl_xor(s, 1, 64);
      s += __shfl_xor(s, 2, 64);
      s += __shfl_xor(s, 4, 64);
      s += __shfl_xor(s, 8, 64);
      if ((lane & 15) == 0) {
        size_t idx = (size_t)comp * NN + rbase + mi * 16 + (lane >> 4) * 4 + reg;
        s2b[idx] = 0.5f * s + r1[idx] + r2[idx];
      }
    }
  }
}

// ---------------- R: online logsumexp over K ----------------
__global__ __launch_bounds__(256) void mfa_lse(const float* __restrict__ s2b,
                                               float* __restrict__ out) {
  int n = blockIdx.x * 256 + threadIdx.x;
  float m = -3.0e38f, s = 0.f;
#pragma unroll 8
  for (int k = 0; k < KC; ++k) {
    float t = s2b[(size_t)k * NN + n];
    float nm = fmaxf(m, t);
    s = s * expf(m - nm) + expf(t - nm);
    m = nm;
  }
  out[n] = m + logf(s);
}

extern "C" void kernel_launch(void* const* d_in, const int* in_sizes, int n_in,
                              void* d_out, int out_size, void* d_ws, size_t ws_size,
                              hipStream_t stream) {
  const float* x  = (const float*)d_in[0];
  const float* MU = (const float*)d_in[1];
  const float* A  = (const float*)d_in[2];
  const float* Dp = (const float*)d_in[3];
  const float* PI = (const float*)d_in[4];
  float* out = (float*)d_out;

  char* base = (char*)d_ws;
  size_t off = 0;
  auto alloc = [&](size_t bytes) -> void* {
    void* p = base + off;
    off += (bytes + 255) & ~(size_t)255;
    return p;
  };
  unsigned short* xbf  = (unsigned short*)alloc((size_t)NN * DF * 2);
  unsigned short* x2bf = (unsigned short*)alloc((size_t)NN * DF * 2);
  float* iDf           = (float*)alloc((size_t)KC * DF * 4);
  unsigned short* iDbf = (unsigned short*)alloc((size_t)KC * DF * 2);
  unsigned short* wbf  = (unsigned short*)alloc((size_t)KC * DF * 2);
  float* miDf          = (float*)alloc((size_t)KC * DF * 4);
  float* m2p           = (float*)alloc((size_t)2 * KC * 64 * 4);
  float* c0a           = (float*)alloc((size_t)KC * 4);
  float* c0            = (float*)alloc((size_t)KC * 4);
  float* Lp            = (float*)alloc((size_t)2 * KC * 4096 * 4);  // dead after chol
  float* Winv          = (float*)alloc((size_t)KC * 4096 * 4);
  float* hws           = (float*)alloc((size_t)KC * 64 * 4);
  unsigned short* Gt   = (unsigned short*)alloc((size_t)KC * 64 * DF * 2);
  float* s2b           = (float*)alloc((size_t)KC * NN * 4);
  // alias r1/r2 over Lp (Lp only read by mfa_chol, which runs before mfa_q1)
  float* r1 = Lp;
  float* r2 = Lp + (size_t)KC * 4096;

  mfa_convert<<<NN * DF / 1024, 256, 0, stream>>>(x, xbf, x2bf);
  mfa_stats<<<KC, 256, 0, stream>>>(MU, Dp, PI, iDf, iDbf, wbf, miDf, c0a);
  mfa_lmat<<<dim3(KC, 2), 256, 0, stream>>>(A, iDf, miDf, Lp, m2p);
  mfa_chol<<<KC, 256, 0, stream>>>(Lp, m2p, c0a, Winv, hws, c0);
  mfa_gt<<<dim3(KC, 4), 256, 0, stream>>>(A, iDf, Winv, Gt);
  mfa_q1<<<dim3(NN / 128, 2), 256, 0, stream>>>(xbf, x2bf, wbf, iDbf, c0, r1, r2);
  mfa_main<<<dim3(64, 32), 256, 0, stream>>>(xbf, Gt, hws, r1, r2, s2b);
  mfa_lse<<<NN / 256, 256, 0, stream>>>(s2b, out);
}

// Round 3
// 239.873 us; speedup vs baseline: 1.1844x; 1.1844x over previous
//
#include <hip/hip_runtime.h>
#include <math.h>

// MFA Woodbury log-likelihood:
//   per_comp[k,n] = c0_k + x.w_k - 0.5*x^2.iD_k + 0.5*||G_k^T x - h_k||^2
//   out[n] = logsumexp_k per_comp[k,n]
// L = I + A^T diag(iD) A = C C^T; Winv = C^{-1}; Gt = Winv AiD^T; h = Winv (AiD^T mu)
// 4 dispatches: setup (per-k everything), q1g (r12 GEMM), main (big GEMM + SSQ), lse.

#define KC 128
#define DF 512
#define LF 64
#define NN 4096

typedef __attribute__((ext_vector_type(8))) short short8;
typedef __attribute__((ext_vector_type(4))) float f32x4;

static __device__ __forceinline__ unsigned short bfr(float f) {
  union { float f; unsigned u; } v; v.f = f;
  return (unsigned short)((v.u + 0x7FFFu + ((v.u >> 16) & 1u)) >> 16);
}

static __device__ __forceinline__ void ldst16(void* lds, const void* g) {
  __builtin_amdgcn_global_load_lds((const __attribute__((address_space(1))) void*)g,
                                   (__attribute__((address_space(3))) void*)lds,
                                   16, 0, 0);
}

// ============ SETUP: one block per k (512 thr): convert-slice, stats, L, chol,
// Winv (register-unrolled), h, Gt ============
__global__ __launch_bounds__(512) void mfa_setup(const float* __restrict__ x,
                                                 const float* __restrict__ MU,
                                                 const float* __restrict__ A,
                                                 const float* __restrict__ Dp,
                                                 const float* __restrict__ PI,
                                                 unsigned short* __restrict__ xaug,
                                                 unsigned short* __restrict__ Waug,
                                                 unsigned short* __restrict__ Gt,
                                                 float* __restrict__ hws,
                                                 float* __restrict__ c0g) {
  int k = blockIdx.x, tid = threadIdx.x;
  __shared__ float iDs[DF];
  __shared__ float miDs[DF];
  __shared__ float scratch[64 * 72];
  __shared__ float Cm[64 * 65];
  __shared__ float m2p[512];
  __shared__ float m2f[64];
  __shared__ float invd_s[64];
  __shared__ float redq[64];
  __shared__ float c0a_s;

  // ---- phase 0: convert n-slice [k*32, k*32+32) -> xaug=[x | x^2] bf16 ----
  const float4* x4 = reinterpret_cast<const float4*>(x);
#pragma unroll
  for (int it = 0; it < 8; ++it) {
    int f = it * 512 + tid;            // float4 id within slice, 0..4095
    int n = k * 32 + (f >> 7);
    int c4 = (f & 127) << 2;
    float4 v = x4[(size_t)n * 128 + (f & 127)];
    ushort4 a, b;
    a.x = bfr(v.x); a.y = bfr(v.y); a.z = bfr(v.z); a.w = bfr(v.w);
    b.x = bfr(v.x * v.x); b.y = bfr(v.y * v.y); b.z = bfr(v.z * v.z); b.w = bfr(v.w * v.w);
    *reinterpret_cast<ushort4*>(&xaug[(size_t)n * 1024 + c4]) = a;
    *reinterpret_cast<ushort4*>(&xaug[(size_t)n * 1024 + 512 + c4]) = b;
  }

  // ---- phase 1: stats ----
  {
    int d = tid;  // 512 threads = 512 d
    float Dv = Dp[k * DF + d];
    float id = 1.f / (Dv * Dv);
    float mu = MU[k * DF + d];
    float wv = id * mu;
    iDs[d] = id;
    miDs[d] = wv;
    Waug[(size_t)k * 1024 + d] = bfr(wv);
    Waug[(size_t)k * 1024 + 512 + d] = bfr(-0.5f * id);
    float slog = logf(id);
    float smu2 = wv * mu;
#pragma unroll
    for (int m = 1; m < 64; m <<= 1) {
      slog += __shfl_xor(slog, m, 64);
      smu2 += __shfl_xor(smu2, m, 64);
    }
    if ((tid & 63) == 0) { redq[tid >> 6] = slog; redq[8 + (tid >> 6)] = smu2; }
  }
  __syncthreads();
  if (tid == 0) {
    float sl = 0.f, sm = 0.f;
    for (int q = 0; q < 8; ++q) { sl += redq[q]; sm += redq[8 + q]; }
    c0a_s = PI[k] - 0.5f * (DF * 1.8378770664093453f + sm - sl);
  }

  // ---- phase 2: L = A^T diag(iD) A (+I), m2 = AiD^T mu ----
  float acc[2][4];
#pragma unroll
  for (int a = 0; a < 2; ++a)
#pragma unroll
    for (int b = 0; b < 4; ++b) acc[a][b] = 0.f;
  float m2acc = 0.f;
  int ti2 = tid >> 4;            // 0..31 -> rows 2*ti2, 2*ti2+1
  int tj2 = (tid & 15) * 4;      // cols tj2..tj2+3
  int mi_i = tid & 63, mi_g = tid >> 6;
  for (int ch = 0; ch < 8; ++ch) {
    __syncthreads();
#pragma unroll
    for (int q = 0; q < 2; ++q) {
      int f = q * 512 + tid;     // float4 id 0..1023
      int dd = f >> 4, i4 = (f & 15) * 4;
      float4 v = *reinterpret_cast<const float4*>(&A[((size_t)(k * DF + ch * 64 + dd)) * LF + i4]);
      *reinterpret_cast<f32x4*>(&scratch[dd * 72 + i4]) = *reinterpret_cast<f32x4*>(&v);
    }
    __syncthreads();
#pragma unroll 8
    for (int d = 0; d < 64; ++d) {
      float idv = iDs[ch * 64 + d];
      float a0 = scratch[d * 72 + 2 * ti2] * idv;
      float a1 = scratch[d * 72 + 2 * ti2 + 1] * idv;
      f32x4 aj = *reinterpret_cast<const f32x4*>(&scratch[d * 72 + tj2]);
      acc[0][0] += a0 * aj[0]; acc[0][1] += a0 * aj[1]; acc[0][2] += a0 * aj[2]; acc[0][3] += a0 * aj[3];
      acc[1][0] += a1 * aj[0]; acc[1][1] += a1 * aj[1]; acc[1][2] += a1 * aj[2]; acc[1][3] += a1 * aj[3];
    }
#pragma unroll
    for (int dd = 0; dd < 8; ++dd) {
      int d = mi_g * 8 + dd;
      m2acc += scratch[d * 72 + mi_i] * miDs[ch * 64 + d];
    }
  }
  __syncthreads();
#pragma unroll
  for (int a = 0; a < 2; ++a)
#pragma unroll
    for (int b = 0; b < 4; ++b) {
      int rr = 2 * ti2 + a, cc = tj2 + b;
      Cm[rr * 65 + cc] = acc[a][b] + (rr == cc ? 1.f : 0.f);
    }
  m2p[tid] = m2acc;
  __syncthreads();
  if (tid < 64) {
    float s = 0.f;
#pragma unroll
    for (int g = 0; g < 8; ++g) s += m2p[g * 64 + tid];
    m2f[tid] = s;
  }

  // ---- phase 3: scale-free right-looking Cholesky (diag raw, lower unscaled) ----
  int tr = tid >> 4, tc = tid & 15;
  for (int j = 0; j < 64; ++j) {
    __syncthreads();
    float v = Cm[j * 65 + j];
    float rinv = 1.0f / v;
#pragma unroll
    for (int a = 0; a < 2; ++a) {
      int r = j + 1 + tr + 32 * a;
      if (r < 64) {
        float crj = Cm[r * 65 + j] * rinv;
#pragma unroll
        for (int b = 0; b < 4; ++b) {
          int c = j + 1 + tc + 16 * b;
          if (c < 64) Cm[r * 65 + c] -= crj * Cm[c * 65 + j];
        }
      }
    }
  }
  __syncthreads();
  if (tid < 64) {
    float dg = Cm[tid * 65 + tid];
    invd_s[tid] = rsqrtf(dg);
    redq[tid] = logf(dg);          // sum = logdet(L)
  }
  __syncthreads();
  if (tid == 0) {
    float s = 0.f;
    for (int q = 0; q < 64; ++q) s += redq[q];
    c0g[k] = c0a_s - 0.5f * s;
  }
  __syncthreads();

  // ---- phase 5: Winv = C^{-1}, column per thread, fully register-unrolled.
  // Unscaled chol: C[r][i] = Cm[r][i]*invd[i]. Writes overwrite Cm in-place:
  // iteration r reads row r before any thread writes row r (single wave, in order).
  if (tid < 64) {
    int jc = tid;
    float w2[64];
#pragma unroll
    for (int r = 0; r < 64; ++r) {
      float s = (r == jc) ? 1.0f : 0.0f;
#pragma unroll
      for (int i = 0; i < r; ++i) s -= Cm[r * 65 + i] * w2[i];
      float idr = invd_s[r];
      float wr = s * idr;
      Cm[r * 65 + jc] = wr;        // Winv[r][jc]; zero for r<jc
      w2[r] = wr * idr;
    }
  }
  __syncthreads();

  // ---- phase 6: h = Winv * m2 ----
  if (tid < 64) {
    float hsum = 0.f;
#pragma unroll
    for (int j2 = 0; j2 < 64; ++j2) hsum += Cm[tid * 65 + j2] * m2f[j2];
    hws[k * 64 + tid] = hsum;
  }

  // ---- phase 7: Gt[l][d] = iD[d] * sum_i Winv[l][i] * A[d][i], bf16 ----
  int l = tid & 63, dg = tid >> 6;
  for (int ch = 0; ch < 8; ++ch) {
    __syncthreads();
#pragma unroll
    for (int q = 0; q < 2; ++q) {
      int f = q * 512 + tid;
      int dd = f >> 4, i4 = (f & 15) * 4;
      float4 v = *reinterpret_cast<const float4*>(&A[((size_t)(k * DF + ch * 64 + dd)) * LF + i4]);
      scratch[(i4 + 0) * 72 + dd] = v.x;
      scratch[(i4 + 1) * 72 + dd] = v.y;
      scratch[(i4 + 2) * 72 + dd] = v.z;
      scratch[(i4 + 3) * 72 + dd] = v.w;
    }
    __syncthreads();
    float o[8];
#pragma unroll
    for (int e = 0; e < 8; ++e) o[e] = 0.f;
#pragma unroll 16
    for (int i = 0; i < 64; ++i) {
      float wv = Cm[l * 65 + i];
      f32x4 a0 = *reinterpret_cast<const f32x4*>(&scratch[i * 72 + dg * 8]);
      f32x4 a1 = *reinterpret_cast<const f32x4*>(&scratch[i * 72 + dg * 8 + 4]);
      o[0] += wv * a0[0]; o[1] += wv * a0[1]; o[2] += wv * a0[2]; o[3] += wv * a0[3];
      o[4] += wv * a1[0]; o[5] += wv * a1[1]; o[6] += wv * a1[2]; o[7] += wv * a1[3];
    }
    unsigned short t8[8];
#pragma unroll
    for (int e = 0; e < 8; ++e) t8[e] = bfr(o[e] * iDs[ch * 64 + dg * 8 + e]);
    uint4 val;
    val.x = (unsigned)t8[0] | ((unsigned)t8[1] << 16);
    val.y = (unsigned)t8[2] | ((unsigned)t8[3] << 16);
    val.z = (unsigned)t8[4] | ((unsigned)t8[5] << 16);
    val.w = (unsigned)t8[6] | ((unsigned)t8[7] << 16);
    *reinterpret_cast<uint4*>(&Gt[((size_t)(k * 64 + l)) * DF + ch * 64 + dg * 8]) = val;
  }
}

// ============ Q1G: r12 partials = xaug(4096x1024) @ Waug^T(128x1024), K-split x4 ============
__global__ __launch_bounds__(256) void mfa_q1g(const unsigned short* __restrict__ xaug,
                                               const unsigned short* __restrict__ Waug,
                                               float* __restrict__ r12p) {
  int nb = blockIdx.x * 128, kq = blockIdx.y;
  int tid = threadIdx.x, lane = tid & 63, w = tid >> 6, wx = w & 1, wy = w >> 1;
  __shared__ unsigned short As[128 * 64];
  __shared__ unsigned short Bs[128 * 64];
  f32x4 acc[4][4];
  f32x4 zero = {0.f, 0.f, 0.f, 0.f};
#pragma unroll
  for (int mi = 0; mi < 4; ++mi)
#pragma unroll
    for (int nj = 0; nj < 4; ++nj) acc[mi][nj] = zero;
  const unsigned short* xg = xaug + (size_t)nb * 1024;
  int lr = lane >> 3, lc = lane & 7;
  int gcs = (lc ^ lr) * 8;
  for (int kt = 0; kt < 4; ++kt) {
    int kof = kq * 256 + kt * 64;
#pragma unroll
    for (int it = 0; it < 4; ++it) {
      int row = w * 8 + it * 32 + lr;
      ldst16(&As[(w * 8 + it * 32) * 64], xg + (size_t)row * 1024 + kof + gcs);
      ldst16(&Bs[(w * 8 + it * 32) * 64], Waug + (size_t)row * 1024 + kof + gcs);
    }
    __syncthreads();
#pragma unroll
    for (int kk = 0; kk < 2; ++kk) {
      int sw = ((kk * 4 + (lane >> 4)) ^ (lane & 7)) * 8;
      short8 av[4], bv[4];
#pragma unroll
      for (int mi = 0; mi < 4; ++mi)
        av[mi] = *reinterpret_cast<const short8*>(&As[(wy * 64 + mi * 16 + (lane & 15)) * 64 + sw]);
#pragma unroll
      for (int nj = 0; nj < 4; ++nj)
        bv[nj] = *reinterpret_cast<const short8*>(&Bs[(wx * 64 + nj * 16 + (lane & 15)) * 64 + sw]);
#pragma unroll
      for (int mi = 0; mi < 4; ++mi)
#pragma unroll
        for (int nj = 0; nj < 4; ++nj)
          acc[mi][nj] = __builtin_amdgcn_mfma_f32_16x16x32_bf16(av[mi], bv[nj], acc[mi][nj], 0, 0, 0);
    }
    __syncthreads();
  }
  float* outp = r12p + (size_t)kq * KC * NN;
#pragma unroll
  for (int mi = 0; mi < 4; ++mi)
#pragma unroll
    for (int nj = 0; nj < 4; ++nj) {
      int ccol = wx * 64 + nj * 16 + (lane & 15);
      int nrow = nb + wy * 64 + mi * 16 + (lane >> 4) * 4;
      float4 o;
      o.x = acc[mi][nj][0]; o.y = acc[mi][nj][1]; o.z = acc[mi][nj][2]; o.w = acc[mi][nj][3];
      *reinterpret_cast<float4*>(&outp[(size_t)ccol * NN + nrow]) = o;
    }
}

// ============ MAIN: x @ Gt^T + fused 0.5||u-h||^2 + c0 + r12 ============
__global__ __launch_bounds__(256) void mfa_main(const unsigned short* __restrict__ xaug,
                                                const unsigned short* __restrict__ Gt,
                                                const float* __restrict__ hws,
                                                const float* __restrict__ c0g,
                                                const float* __restrict__ r12p,
                                                float* __restrict__ s2b) {
  int bx = blockIdx.x, by = blockIdx.y;
  int tid = threadIdx.x, lane = tid & 63, w = tid >> 6, wx = w & 1, wy = w >> 1;
  __shared__ unsigned short As[128 * 64];
  __shared__ unsigned short Bs[128 * 64];
  f32x4 acc[4][4];
  f32x4 zero = {0.f, 0.f, 0.f, 0.f};
#pragma unroll
  for (int mi = 0; mi < 4; ++mi)
#pragma unroll
    for (int nj = 0; nj < 4; ++nj) acc[mi][nj] = zero;
  int nbase = by * 128, cbase = bx * 128;
  const unsigned short* xg = xaug + (size_t)nbase * 1024;
  const unsigned short* gg = Gt + (size_t)cbase * DF;
  int lr = lane >> 3, lc = lane & 7;
  int gcs = (lc ^ lr) * 8;
  for (int kt = 0; kt < 8; ++kt) {
#pragma unroll
    for (int it = 0; it < 4; ++it) {
      int row = w * 8 + it * 32 + lr;
      ldst16(&As[(w * 8 + it * 32) * 64], xg + (size_t)row * 1024 + kt * 64 + gcs);
      ldst16(&Bs[(w * 8 + it * 32) * 64], gg + (size_t)row * DF + kt * 64 + gcs);
    }
    __syncthreads();
#pragma unroll
    for (int kk = 0; kk < 2; ++kk) {
      int sw = ((kk * 4 + (lane >> 4)) ^ (lane & 7)) * 8;
      short8 av[4], bv[4];
#pragma unroll
      for (int mi = 0; mi < 4; ++mi)
        av[mi] = *reinterpret_cast<const short8*>(&As[(wy * 64 + mi * 16 + (lane & 15)) * 64 + sw]);
#pragma unroll
      for (int nj = 0; nj < 4; ++nj)
        bv[nj] = *reinterpret_cast<const short8*>(&Bs[(wx * 64 + nj * 16 + (lane & 15)) * 64 + sw]);
#pragma unroll
      for (int mi = 0; mi < 4; ++mi)
#pragma unroll
        for (int nj = 0; nj < 4; ++nj)
          acc[mi][nj] = __builtin_amdgcn_mfma_f32_16x16x32_bf16(av[mi], bv[nj], acc[mi][nj], 0, 0, 0);
    }
    __syncthreads();
  }
  // epilogue: per-wave component; 0.5*sum(u-h)^2 + c0 + r12 partials
  int comp = bx * 2 + wx;
  float hv[4];
#pragma unroll
  for (int nj = 0; nj < 4; ++nj) hv[nj] = hws[comp * 64 + nj * 16 + (lane & 15)];
  float cc = c0g[comp];
  int rbase = nbase + wy * 64;
#pragma unroll
  for (int mi = 0; mi < 4; ++mi) {
    f32x4 sv;
#pragma unroll
    for (int reg = 0; reg < 4; ++reg) {
      float s = 0.f;
#pragma unroll
      for (int nj = 0; nj < 4; ++nj) {
        float dlt = acc[mi][nj][reg] - hv[nj];
        s += dlt * dlt;
      }
      s += __shfl_xor(s, 1, 64);
      s += __shfl_xor(s, 2, 64);
      s += __shfl_xor(s, 4, 64);
      s += __shfl_xor(s, 8, 64);
      sv[reg] = s;
    }
    if ((lane & 15) == 0) {
      int nr = rbase + mi * 16 + (lane >> 4) * 4;
      size_t idx = (size_t)comp * NN + nr;
      float4 r0 = *reinterpret_cast<const float4*>(&r12p[idx]);
      float4 r1 = *reinterpret_cast<const float4*>(&r12p[(size_t)KC * NN + idx]);
      float4 r2 = *reinterpret_cast<const float4*>(&r12p[(size_t)2 * KC * NN + idx]);
      float4 r3 = *reinterpret_cast<const float4*>(&r12p[(size_t)3 * KC * NN + idx]);
      float4 o;
      o.x = 0.5f * sv[0] + cc + r0.x + r1.x + r2.x + r3.x;
      o.y = 0.5f * sv[1] + cc + r0.y + r1.y + r2.y + r3.y;
      o.z = 0.5f * sv[2] + cc + r0.z + r1.z + r2.z + r3.z;
      o.w = 0.5f * sv[3] + cc + r0.w + r1.w + r2.w + r3.w;
      *reinterpret_cast<float4*>(&s2b[idx]) = o;
    }
  }
}

// ============ LSE over K ============
__global__ __launch_bounds__(64) void mfa_lse(const float* __restrict__ s2b,
                                              float* __restrict__ out) {
  int n = blockIdx.x * 64 + threadIdx.x;
  float m = -3.0e38f, s = 0.f;
#pragma unroll 8
  for (int k = 0; k < KC; ++k) {
    float t = s2b[(size_t)k * NN + n];
    float nm = fmaxf(m, t);
    s = s * expf(m - nm) + expf(t - nm);
    m = nm;
  }
  out[n] = m + logf(s);
}

extern "C" void kernel_launch(void* const* d_in, const int* in_sizes, int n_in,
                              void* d_out, int out_size, void* d_ws, size_t ws_size,
                              hipStream_t stream) {
  const float* x  = (const float*)d_in[0];
  const float* MU = (const float*)d_in[1];
  const float* A  = (const float*)d_in[2];
  const float* Dp = (const float*)d_in[3];
  const float* PI = (const float*)d_in[4];
  float* out = (float*)d_out;

  char* base = (char*)d_ws;
  size_t off = 0;
  auto alloc = [&](size_t bytes) -> void* {
    void* p = base + off;
    off += (bytes + 255) & ~(size_t)255;
    return p;
  };
  unsigned short* xaug = (unsigned short*)alloc((size_t)NN * 1024 * 2);   // 8 MB
  unsigned short* Waug = (unsigned short*)alloc((size_t)KC * 1024 * 2);   // 256 KB
  unsigned short* Gt   = (unsigned short*)alloc((size_t)KC * 64 * DF * 2);// 8 MB
  float* hws           = (float*)alloc((size_t)KC * 64 * 4);
  float* c0g           = (float*)alloc((size_t)KC * 4);
  float* r12p          = (float*)alloc((size_t)4 * KC * NN * 4);          // 8 MB
  float* s2b           = (float*)alloc((size_t)KC * NN * 4);              // 2 MB

  mfa_setup<<<KC, 512, 0, stream>>>(x, MU, A, Dp, PI, xaug, Waug, Gt, hws, c0g);
  mfa_q1g<<<dim3(NN / 128, 4), 256, 0, stream>>>(xaug, Waug, r12p);
  mfa_main<<<dim3(64, NN / 128), 256, 0, stream>>>(xaug, Gt, hws, c0g, r12p, s2b);
  mfa_lse<<<NN / 64, 64, 0, stream>>>(s2b, out);
}

// Round 5
// 214.914 us; speedup vs baseline: 1.3220x; 1.1161x over previous
//
#include <hip/hip_runtime.h>
#include <math.h>

// MFA Woodbury log-likelihood:
//   per_comp[k,n] = c0_k + x.w_k - 0.5*x^2.iD_k + 0.5*||G_k^T x - h_k||^2
//   out[n] = logsumexp_k per_comp[k,n]
// As = sqrt(iD) .* A (bf16); L = As^T As + I = C C^T; Winv = C^{-1} (bf16 Wb)
// Gt = sqrt(iD) .* (Winv As^T); h = Winv (As^T smu), smu = sqrt(iD)*mu
// 6 dispatches: prep, percomp (L-syrk+chol+Winv+h), gt, q1g, main, lse.

#define KC 128
#define DF 512
#define LF 64
#define NN 4096

typedef __attribute__((ext_vector_type(8))) short short8;
typedef __attribute__((ext_vector_type(4))) float f32x4;

static __device__ __forceinline__ unsigned short bfr(float f) {
  union { float f; unsigned u; } v; v.f = f;
  return (unsigned short)((v.u + 0x7FFFu + ((v.u >> 16) & 1u)) >> 16);
}
static __device__ __forceinline__ float b2f(unsigned short u) {
  union { unsigned u; float f; } v; v.u = ((unsigned)u) << 16; return v.f;
}
static __device__ __forceinline__ void ldst16(void* lds, const void* g) {
  __builtin_amdgcn_global_load_lds((const __attribute__((address_space(1))) void*)g,
                                   (__attribute__((address_space(3))) void*)lds,
                                   16, 0, 0);
}

// ============ PREP: x -> xaug=[x|x^2] bf16 ; A -> As (d-major) + Ast (i-major) ============
__global__ __launch_bounds__(256) void mfa_prep(const float* __restrict__ x,
                                                const float* __restrict__ A,
                                                const float* __restrict__ Dp,
                                                unsigned short* __restrict__ xaug,
                                                unsigned short* __restrict__ As,
                                                unsigned short* __restrict__ Ast) {
  int b = blockIdx.x, tid = threadIdx.x;
  if (b < 1024) {
    int k = b >> 3, dc = b & 7;
    __shared__ float siDs[64];
    __shared__ unsigned short Tr[64][72];
    if (tid < 64) siDs[tid] = 1.0f / Dp[k * DF + dc * 64 + tid];
    __syncthreads();
#pragma unroll
    for (int q = 0; q < 4; ++q) {
      int f = q * 256 + tid;
      int dd = f >> 4, i4 = (f & 15) * 4;
      float4 v = *reinterpret_cast<const float4*>(&A[((size_t)(k * DF + dc * 64 + dd)) * LF + i4]);
      float s = siDs[dd];
      ushort4 u;
      u.x = bfr(v.x * s); u.y = bfr(v.y * s); u.z = bfr(v.z * s); u.w = bfr(v.w * s);
      *reinterpret_cast<ushort4*>(&As[((size_t)(k * DF + dc * 64 + dd)) * LF + i4]) = u;
      *reinterpret_cast<ushort4*>(&Tr[dd][i4]) = u;
    }
    __syncthreads();
    int i = tid >> 2, ds0 = (tid & 3) * 16;
    unsigned short t16[16];
#pragma unroll
    for (int e = 0; e < 16; ++e) t16[e] = Tr[ds0 + e][i];
    uint4 v0, v1;
    v0.x = (unsigned)t16[0] | ((unsigned)t16[1] << 16);
    v0.y = (unsigned)t16[2] | ((unsigned)t16[3] << 16);
    v0.z = (unsigned)t16[4] | ((unsigned)t16[5] << 16);
    v0.w = (unsigned)t16[6] | ((unsigned)t16[7] << 16);
    v1.x = (unsigned)t16[8] | ((unsigned)t16[9] << 16);
    v1.y = (unsigned)t16[10] | ((unsigned)t16[11] << 16);
    v1.z = (unsigned)t16[12] | ((unsigned)t16[13] << 16);
    v1.w = (unsigned)t16[14] | ((unsigned)t16[15] << 16);
    size_t ro = ((size_t)(k * LF + i)) * DF + dc * 64 + ds0;
    *reinterpret_cast<uint4*>(&Ast[ro]) = v0;
    *reinterpret_cast<uint4*>(&Ast[ro + 8]) = v1;
  } else {
    int f = (b - 1024) * 256 + tid;      // float4 index over NN*DF/4
    float4 v = reinterpret_cast<const float4*>(x)[f];
    int n = f >> 7, c4 = (f & 127) << 2;
    ushort4 a, s;
    a.x = bfr(v.x); a.y = bfr(v.y); a.z = bfr(v.z); a.w = bfr(v.w);
    s.x = bfr(v.x * v.x); s.y = bfr(v.y * v.y); s.z = bfr(v.z * v.z); s.w = bfr(v.w * v.w);
    *reinterpret_cast<ushort4*>(&xaug[(size_t)n * 1024 + c4]) = a;
    *reinterpret_cast<ushort4*>(&xaug[(size_t)n * 1024 + 512 + c4]) = s;
  }
}

// ============ PERCOMP: per k — L via MFMA syrk, stats, m2, chol, Winv, h, c0, Wb ============
__global__ __launch_bounds__(256) void mfa_percomp(const float* __restrict__ MU,
                                                   const float* __restrict__ Dp,
                                                   const float* __restrict__ PI,
                                                   const unsigned short* __restrict__ Ast,
                                                   unsigned short* __restrict__ Waug,
                                                   unsigned short* __restrict__ Wb,
                                                   float* __restrict__ hws,
                                                   float* __restrict__ c0g) {
  int k = blockIdx.x, tid = threadIdx.x, lane = tid & 63, w = tid >> 6;
  __shared__ unsigned short Tile[64 * 64];
  __shared__ float Cm[64 * 65];
  __shared__ float smuS[DF];
  __shared__ float m2part[256];
  __shared__ float m2S[64];
  __shared__ float invd_s[64];
  __shared__ float redq[80];
  __shared__ float c0a_s;

  // ---- phase A: L = Ast Ast^T via bf16 MFMA (K=512) ----
  f32x4 accL[4];
  f32x4 zero = {0.f, 0.f, 0.f, 0.f};
#pragma unroll
  for (int nj = 0; nj < 4; ++nj) accL[nj] = zero;
  int lr = lane >> 3, lc = lane & 7;
  int gcs = (lc ^ lr) * 8;
  for (int kt = 0; kt < 8; ++kt) {
#pragma unroll
    for (int it = 0; it < 2; ++it) {
      int row = w * 8 + it * 32 + lr;
      ldst16(&Tile[(w * 8 + it * 32) * 64], Ast + ((size_t)(k * LF + row)) * DF + kt * 64 + gcs);
    }
    __syncthreads();
#pragma unroll
    for (int kk = 0; kk < 2; ++kk) {
      int sw = ((kk * 4 + (lane >> 4)) ^ (lane & 7)) * 8;
      short8 av = *reinterpret_cast<const short8*>(&Tile[(w * 16 + (lane & 15)) * 64 + sw]);
#pragma unroll
      for (int nj = 0; nj < 4; ++nj) {
        short8 bv = *reinterpret_cast<const short8*>(&Tile[(nj * 16 + (lane & 15)) * 64 + sw]);
        accL[nj] = __builtin_amdgcn_mfma_f32_16x16x32_bf16(av, bv, accL[nj], 0, 0, 0);
      }
    }
    __syncthreads();
  }
#pragma unroll
  for (int nj = 0; nj < 4; ++nj)
#pragma unroll
    for (int reg = 0; reg < 4; ++reg) {
      int m = w * 16 + (lane >> 4) * 4 + reg;
      int n = nj * 16 + (lane & 15);
      Cm[m * 65 + n] = accL[nj][reg] + (m == n ? 1.f : 0.f);
    }

  // ---- phase B: stats, smu, Waug ----
  {
    float slog = 0.f, smu2 = 0.f;
#pragma unroll
    for (int p = 0; p < 2; ++p) {
      int d = p * 256 + tid;
      float Dv = Dp[k * DF + d];
      float id = 1.f / (Dv * Dv);
      float mu = MU[k * DF + d];
      float wv = id * mu;
      smuS[d] = mu / Dv;
      Waug[(size_t)k * 1024 + d] = bfr(wv);
      Waug[(size_t)k * 1024 + 512 + d] = bfr(-0.5f * id);
      slog += logf(id);
      smu2 += wv * mu;
    }
#pragma unroll
    for (int m = 1; m < 64; m <<= 1) {
      slog += __shfl_xor(slog, m, 64);
      smu2 += __shfl_xor(smu2, m, 64);
    }
    if (lane == 0) { redq[w] = slog; redq[8 + w] = smu2; }
  }
  __syncthreads();
  if (tid == 0) {
    float sl = 0.f, sm = 0.f;
    for (int q = 0; q < 4; ++q) { sl += redq[q]; sm += redq[8 + q]; }
    c0a_s = PI[k] - 0.5f * (DF * 1.8378770664093453f + sm - sl);
  }

  // ---- phase C: m2[i] = sum_d Ast[i][d]*smu[d]  (128 d per thread = 64 uints) ----
  {
    int i = tid & 63, dg = tid >> 6;
    float acc = 0.f;
    const unsigned* up = reinterpret_cast<const unsigned*>(Ast + ((size_t)(k * LF + i)) * DF + dg * 128);
#pragma unroll
    for (int q = 0; q < 64; ++q) {
      unsigned uu = up[q];
      int d0 = dg * 128 + q * 2;
      acc += b2f((unsigned short)(uu & 0xFFFF)) * smuS[d0];
      acc += b2f((unsigned short)(uu >> 16)) * smuS[d0 + 1];
    }
    m2part[tid] = acc;
  }
  __syncthreads();
  if (tid < 64) m2S[tid] = m2part[tid] + m2part[tid + 64] + m2part[tid + 128] + m2part[tid + 192];

  // ---- phase D: scale-free right-looking Cholesky (diag raw) ----
  int tr = tid >> 4, tc = tid & 15;
  for (int j = 0; j < 64; ++j) {
    __syncthreads();
    float rinv = 1.0f / Cm[j * 65 + j];
#pragma unroll
    for (int a = 0; a < 4; ++a) {
      int r = j + 1 + tr + 16 * a;
      if (r < 64) {
        float crj = Cm[r * 65 + j] * rinv;
#pragma unroll
        for (int bb = 0; bb < 4; ++bb) {
          int c = j + 1 + tc + 16 * bb;
          if (c < 64) Cm[r * 65 + c] -= crj * Cm[c * 65 + j];
        }
      }
    }
  }
  __syncthreads();
  if (tid < 64) {
    float dg2 = Cm[tid * 65 + tid];
    invd_s[tid] = rsqrtf(dg2);
    redq[tid] = logf(dg2);
  }
  __syncthreads();
  if (tid == 0) {
    float s = 0.f;
    for (int q = 0; q < 64; ++q) s += redq[q];
    c0g[k] = c0a_s - 0.5f * s;
  }
  // ---- phase E: Winv (wave 0, column per lane, register recurrence) ----
  if (tid < 64) {
    int jc = tid;
    float w2[64];
#pragma unroll
    for (int r = 0; r < 64; ++r) {
      float s = (r == jc) ? 1.0f : 0.0f;
#pragma unroll
      for (int i = 0; i < r; ++i) s -= Cm[r * 65 + i] * w2[i];
      float idr = invd_s[r];
      float wr = s * idr;
      Cm[r * 65 + jc] = wr;
      w2[r] = wr * idr;
    }
  }
  // ---- phase F: h = Winv m2 ----
  if (tid < 64) {
    float hsum = 0.f;
#pragma unroll
    for (int j2 = 0; j2 < 64; ++j2) hsum += Cm[tid * 65 + j2] * m2S[j2];
    hws[k * 64 + tid] = hsum;
  }
  __syncthreads();
  // ---- phase G: Wb = bf16(Winv), row-major [l][i] ----
  {
    int l = tid >> 2, seg = (tid & 3) * 16;
    unsigned short t16[16];
#pragma unroll
    for (int e = 0; e < 16; ++e) t16[e] = bfr(Cm[l * 65 + seg + e]);
    uint4 v0, v1;
    v0.x = (unsigned)t16[0] | ((unsigned)t16[1] << 16);
    v0.y = (unsigned)t16[2] | ((unsigned)t16[3] << 16);
    v0.z = (unsigned)t16[4] | ((unsigned)t16[5] << 16);
    v0.w = (unsigned)t16[6] | ((unsigned)t16[7] << 16);
    v1.x = (unsigned)t16[8] | ((unsigned)t16[9] << 16);
    v1.y = (unsigned)t16[10] | ((unsigned)t16[11] << 16);
    v1.z = (unsigned)t16[12] | ((unsigned)t16[13] << 16);
    v1.w = (unsigned)t16[14] | ((unsigned)t16[15] << 16);
    size_t ro = ((size_t)(k * LF + l)) * LF + seg;
    *reinterpret_cast<uint4*>(&Wb[ro]) = v0;
    *reinterpret_cast<uint4*>(&Wb[ro + 8]) = v1;
  }
}

// ============ GT: Gt[l][d] = siD[d] * (Wb @ As^T), MFMA, per (k, d-quarter) ============
__global__ __launch_bounds__(256) void mfa_gt(const unsigned short* __restrict__ Wb,
                                              const unsigned short* __restrict__ As,
                                              const float* __restrict__ Dp,
                                              unsigned short* __restrict__ Gt) {
  int k = blockIdx.x, dq = blockIdx.y;
  int tid = threadIdx.x, lane = tid & 63, w = tid >> 6;
  __shared__ unsigned short Wbs[64 * 64];
  __shared__ unsigned short Ds[128 * 64];
  __shared__ unsigned short Cout[64][132];
  int lr = lane >> 3, lc = lane & 7;
  int gcs = (lc ^ lr) * 8;
#pragma unroll
  for (int it = 0; it < 2; ++it) {
    int row = w * 8 + it * 32 + lr;
    ldst16(&Wbs[(w * 8 + it * 32) * 64], Wb + ((size_t)(k * LF + row)) * LF + gcs);
  }
#pragma unroll
  for (int it = 0; it < 4; ++it) {
    int row = w * 8 + it * 32 + lr;
    ldst16(&Ds[(w * 8 + it * 32) * 64], As + ((size_t)(k * DF + dq * 128 + row)) * LF + gcs);
  }
  __syncthreads();
  f32x4 acc[4][2];
  f32x4 zero = {0.f, 0.f, 0.f, 0.f};
#pragma unroll
  for (int mi = 0; mi < 4; ++mi)
#pragma unroll
    for (int nj = 0; nj < 2; ++nj) acc[mi][nj] = zero;
#pragma unroll
  for (int kk = 0; kk < 2; ++kk) {
    int sw = ((kk * 4 + (lane >> 4)) ^ (lane & 7)) * 8;
    short8 av[4], bv[2];
#pragma unroll
    for (int mi = 0; mi < 4; ++mi)
      av[mi] = *reinterpret_cast<const short8*>(&Wbs[(mi * 16 + (lane & 15)) * 64 + sw]);
#pragma unroll
    for (int nj = 0; nj < 2; ++nj)
      bv[nj] = *reinterpret_cast<const short8*>(&Ds[(w * 32 + nj * 16 + (lane & 15)) * 64 + sw]);
#pragma unroll
    for (int mi = 0; mi < 4; ++mi)
#pragma unroll
      for (int nj = 0; nj < 2; ++nj)
        acc[mi][nj] = __builtin_amdgcn_mfma_f32_16x16x32_bf16(av[mi], bv[nj], acc[mi][nj], 0, 0, 0);
  }
  float siD[2];
#pragma unroll
  for (int nj = 0; nj < 2; ++nj)
    siD[nj] = 1.0f / Dp[k * DF + dq * 128 + w * 32 + nj * 16 + (lane & 15)];
#pragma unroll
  for (int mi = 0; mi < 4; ++mi)
#pragma unroll
    for (int nj = 0; nj < 2; ++nj) {
      int dl = w * 32 + nj * 16 + (lane & 15);
#pragma unroll
      for (int reg = 0; reg < 4; ++reg) {
        int l = mi * 16 + (lane >> 4) * 4 + reg;
        Cout[l][dl] = bfr(acc[mi][nj][reg] * siD[nj]);
      }
    }
  __syncthreads();
  {
    int l = tid >> 2, seg = (tid & 3) * 32;
    uint4* dst = reinterpret_cast<uint4*>(&Gt[((size_t)(k * LF + l)) * DF + dq * 128 + seg]);
#pragma unroll
    for (int u = 0; u < 4; ++u) {
      unsigned short t8[8];
#pragma unroll
      for (int e = 0; e < 8; ++e) t8[e] = Cout[l][seg + u * 8 + e];
      uint4 val;
      val.x = (unsigned)t8[0] | ((unsigned)t8[1] << 16);
      val.y = (unsigned)t8[2] | ((unsigned)t8[3] << 16);
      val.z = (unsigned)t8[4] | ((unsigned)t8[5] << 16);
      val.w = (unsigned)t8[6] | ((unsigned)t8[7] << 16);
      dst[u] = val;
    }
  }
}

// ============ Q1G: r12 partials = xaug(4096x1024) @ Waug^T(128x1024), K-split x4 ============
__global__ __launch_bounds__(256) void mfa_q1g(const unsigned short* __restrict__ xaug,
                                               const unsigned short* __restrict__ Waug,
                                               float* __restrict__ r12p) {
  int nb = blockIdx.x * 128, kq = blockIdx.y;
  int tid = threadIdx.x, lane = tid & 63, w = tid >> 6, wx = w & 1, wy = w >> 1;
  __shared__ unsigned short As[128 * 64];
  __shared__ unsigned short Bs[128 * 64];
  f32x4 acc[4][4];
  f32x4 zero = {0.f, 0.f, 0.f, 0.f};
#pragma unroll
  for (int mi = 0; mi < 4; ++mi)
#pragma unroll
    for (int nj = 0; nj < 4; ++nj) acc[mi][nj] = zero;
  const unsigned short* xg = xaug + (size_t)nb * 1024;
  int lr = lane >> 3, lc = lane & 7;
  int gcs = (lc ^ lr) * 8;
  for (int kt = 0; kt < 4; ++kt) {
    int kof = kq * 256 + kt * 64;
#pragma unroll
    for (int it = 0; it < 4; ++it) {
      int row = w * 8 + it * 32 + lr;
      ldst16(&As[(w * 8 + it * 32) * 64], xg + (size_t)row * 1024 + kof + gcs);
      ldst16(&Bs[(w * 8 + it * 32) * 64], Waug + (size_t)row * 1024 + kof + gcs);
    }
    __syncthreads();
#pragma unroll
    for (int kk = 0; kk < 2; ++kk) {
      int sw = ((kk * 4 + (lane >> 4)) ^ (lane & 7)) * 8;
      short8 av[4], bv[4];
#pragma unroll
      for (int mi = 0; mi < 4; ++mi)
        av[mi] = *reinterpret_cast<const short8*>(&As[(wy * 64 + mi * 16 + (lane & 15)) * 64 + sw]);
#pragma unroll
      for (int nj = 0; nj < 4; ++nj)
        bv[nj] = *reinterpret_cast<const short8*>(&Bs[(wx * 64 + nj * 16 + (lane & 15)) * 64 + sw]);
#pragma unroll
      for (int mi = 0; mi < 4; ++mi)
#pragma unroll
        for (int nj = 0; nj < 4; ++nj)
          acc[mi][nj] = __builtin_amdgcn_mfma_f32_16x16x32_bf16(av[mi], bv[nj], acc[mi][nj], 0, 0, 0);
    }
    __syncthreads();
  }
  float* outp = r12p + (size_t)kq * KC * NN;
#pragma unroll
  for (int mi = 0; mi < 4; ++mi)
#pragma unroll
    for (int nj = 0; nj < 4; ++nj) {
      int ccol = wx * 64 + nj * 16 + (lane & 15);
      int nrow = nb + wy * 64 + mi * 16 + (lane >> 4) * 4;
      float4 o;
      o.x = acc[mi][nj][0]; o.y = acc[mi][nj][1]; o.z = acc[mi][nj][2]; o.w = acc[mi][nj][3];
      *reinterpret_cast<float4*>(&outp[(size_t)ccol * NN + nrow]) = o;
    }
}

// ============ MAIN: x @ Gt^T + fused 0.5||u-h||^2 + c0 + r12 ============
__global__ __launch_bounds__(256) void mfa_main(const unsigned short* __restrict__ xaug,
                                                const unsigned short* __restrict__ Gt,
                                                const float* __restrict__ hws,
                                                const float* __restrict__ c0g,
                                                const float* __restrict__ r12p,
                                                float* __restrict__ s2b) {
  int bx = blockIdx.x, by = blockIdx.y;
  int tid = threadIdx.x, lane = tid & 63, w = tid >> 6, wx = w & 1, wy = w >> 1;
  __shared__ unsigned short As[128 * 64];
  __shared__ unsigned short Bs[128 * 64];
  f32x4 acc[4][4];
  f32x4 zero = {0.f, 0.f, 0.f, 0.f};
#pragma unroll
  for (int mi = 0; mi < 4; ++mi)
#pragma unroll
    for (int nj = 0; nj < 4; ++nj) acc[mi][nj] = zero;
  int nbase = by * 128, cbase = bx * 128;
  const unsigned short* xg = xaug + (size_t)nbase * 1024;
  const unsigned short* gg = Gt + (size_t)cbase * DF;
  int lr = lane >> 3, lc = lane & 7;
  int gcs = (lc ^ lr) * 8;
  for (int kt = 0; kt < 8; ++kt) {
#pragma unroll
    for (int it = 0; it < 4; ++it) {
      int row = w * 8 + it * 32 + lr;
      ldst16(&As[(w * 8 + it * 32) * 64], xg + (size_t)row * 1024 + kt * 64 + gcs);
      ldst16(&Bs[(w * 8 + it * 32) * 64], gg + (size_t)row * DF + kt * 64 + gcs);
    }
    __syncthreads();
#pragma unroll
    for (int kk = 0; kk < 2; ++kk) {
      int sw = ((kk * 4 + (lane >> 4)) ^ (lane & 7)) * 8;
      short8 av[4], bv[4];
#pragma unroll
      for (int mi = 0; mi < 4; ++mi)
        av[mi] = *reinterpret_cast<const short8*>(&As[(wy * 64 + mi * 16 + (lane & 15)) * 64 + sw]);
#pragma unroll
      for (int nj = 0; nj < 4; ++nj)
        bv[nj] = *reinterpret_cast<const short8*>(&Bs[(wx * 64 + nj * 16 + (lane & 15)) * 64 + sw]);
#pragma unroll
      for (int mi = 0; mi < 4; ++mi)
#pragma unroll
        for (int nj = 0; nj < 4; ++nj)
          acc[mi][nj] = __builtin_amdgcn_mfma_f32_16x16x32_bf16(av[mi], bv[nj], acc[mi][nj], 0, 0, 0);
    }
    __syncthreads();
  }
  int comp = bx * 2 + wx;
  float hv[4];
#pragma unroll
  for (int nj = 0; nj < 4; ++nj) hv[nj] = hws[comp * 64 + nj * 16 + (lane & 15)];
  float cc = c0g[comp];
  int rbase = nbase + wy * 64;
#pragma unroll
  for (int mi = 0; mi < 4; ++mi) {
    f32x4 sv;
#pragma unroll
    for (int reg = 0; reg < 4; ++reg) {
      float s = 0.f;
#pragma unroll
      for (int nj = 0; nj < 4; ++nj) {
        float dlt = acc[mi][nj][reg] - hv[nj];
        s += dlt * dlt;
      }
      s += __shfl_xor(s, 1, 64);
      s += __shfl_xor(s, 2, 64);
      s += __shfl_xor(s, 4, 64);
      s += __shfl_xor(s, 8, 64);
      sv[reg] = s;
    }
    if ((lane & 15) == 0) {
      int nr = rbase + mi * 16 + (lane >> 4) * 4;
      size_t idx = (size_t)comp * NN + nr;
      float4 r0 = *reinterpret_cast<const float4*>(&r12p[idx]);
      float4 r1 = *reinterpret_cast<const float4*>(&r12p[(size_t)KC * NN + idx]);
      float4 r2 = *reinterpret_cast<const float4*>(&r12p[(size_t)2 * KC * NN + idx]);
      float4 r3 = *reinterpret_cast<const float4*>(&r12p[(size_t)3 * KC * NN + idx]);
      float4 o;
      o.x = 0.5f * sv[0] + cc + r0.x + r1.x + r2.x + r3.x;
      o.y = 0.5f * sv[1] + cc + r0.y + r1.y + r2.y + r3.y;
      o.z = 0.5f * sv[2] + cc + r0.z + r1.z + r2.z + r3.z;
      o.w = 0.5f * sv[3] + cc + r0.w + r1.w + r2.w + r3.w;
      *reinterpret_cast<float4*>(&s2b[idx]) = o;
    }
  }
}

// ============ LSE over K ============
__global__ __launch_bounds__(64) void mfa_lse(const float* __restrict__ s2b,
                                              float* __restrict__ out) {
  int n = blockIdx.x * 64 + threadIdx.x;
  float m = -3.0e38f, s = 0.f;
#pragma unroll 8
  for (int k = 0; k < KC; ++k) {
    float t = s2b[(size_t)k * NN + n];
    float nm = fmaxf(m, t);
    s = s * expf(m - nm) + expf(t - nm);
    m = nm;
  }
  out[n] = m + logf(s);
}

extern "C" void kernel_launch(void* const* d_in, const int* in_sizes, int n_in,
                              void* d_out, int out_size, void* d_ws, size_t ws_size,
                              hipStream_t stream) {
  const float* x  = (const float*)d_in[0];
  const float* MU = (const float*)d_in[1];
  const float* A  = (const float*)d_in[2];
  const float* Dp = (const float*)d_in[3];
  const float* PI = (const float*)d_in[4];
  float* out = (float*)d_out;

  char* base = (char*)d_ws;
  size_t off = 0;
  auto alloc = [&](size_t bytes) -> void* {
    void* p = base + off;
    off += (bytes + 255) & ~(size_t)255;
    return p;
  };
  unsigned short* xaug = (unsigned short*)alloc((size_t)NN * 1024 * 2);    // 16 MB
  unsigned short* As   = (unsigned short*)alloc((size_t)KC * DF * LF * 2); // 8 MB
  unsigned short* Ast  = (unsigned short*)alloc((size_t)KC * LF * DF * 2); // 8 MB
  unsigned short* Waug = (unsigned short*)alloc((size_t)KC * 1024 * 2);    // 256 KB
  unsigned short* Wb   = (unsigned short*)alloc((size_t)KC * LF * LF * 2); // 1 MB
  unsigned short* Gt   = (unsigned short*)alloc((size_t)KC * LF * DF * 2); // 8 MB
  float* hws           = (float*)alloc((size_t)KC * 64 * 4);
  float* c0g           = (float*)alloc((size_t)KC * 4);
  float* r12p          = (float*)alloc((size_t)4 * KC * NN * 4);           // 8 MB
  float* s2b           = (float*)alloc((size_t)KC * NN * 4);               // 2 MB

  mfa_prep<<<3072, 256, 0, stream>>>(x, A, Dp, xaug, As, Ast);
  mfa_percomp<<<KC, 256, 0, stream>>>(MU, Dp, PI, Ast, Waug, Wb, hws, c0g);
  mfa_gt<<<dim3(KC, 4), 256, 0, stream>>>(Wb, As, Dp, Gt);
  mfa_q1g<<<dim3(NN / 128, 4), 256, 0, stream>>>(xaug, Waug, r12p);
  mfa_main<<<dim3(64, NN / 128), 256, 0, stream>>>(xaug, Gt, hws, c0g, r12p, s2b);
  mfa_lse<<<NN / 64, 64, 0, stream>>>(s2b, out);
}

// Round 6
// 213.961 us; speedup vs baseline: 1.3279x; 1.0045x over previous
//
#include <hip/hip_runtime.h>
#include <math.h>

// MFA Woodbury log-likelihood:
//   per_comp[k,n] = c0_k + x.w_k - 0.5*x^2.iD_k + 0.5*||G_k^T x - h_k||^2
//   out[n] = logsumexp_k per_comp[k,n]
// As = sqrt(iD) .* A (bf16); L = As^T As + I = C C^T; Winv = C^{-1} (bf16 Wb)
// Gt = sqrt(iD) .* (Winv As^T); h = Winv (As^T smu), smu = sqrt(iD)*mu
// 6 dispatches: prep, percomp (stats+syrk/m2+chol+Winv+h), gt, q1g, main, lse.

#define KC 128
#define DF 512
#define LF 64
#define NN 4096

typedef __attribute__((ext_vector_type(8))) short short8;
typedef __attribute__((ext_vector_type(4))) float f32x4;

static __device__ __forceinline__ unsigned short bfr(float f) {
  union { float f; unsigned u; } v; v.f = f;
  return (unsigned short)((v.u + 0x7FFFu + ((v.u >> 16) & 1u)) >> 16);
}
static __device__ __forceinline__ float b2f(unsigned short u) {
  union { unsigned u; float f; } v; v.u = ((unsigned)u) << 16; return v.f;
}
static __device__ __forceinline__ void ldst16(void* lds, const void* g) {
  __builtin_amdgcn_global_load_lds((const __attribute__((address_space(1))) void*)g,
                                   (__attribute__((address_space(3))) void*)lds,
                                   16, 0, 0);
}

// ============ PREP: x -> xaug=[x|x^2] bf16 ; A -> As (d-major) + Ast (i-major) ============
__global__ __launch_bounds__(256) void mfa_prep(const float* __restrict__ x,
                                                const float* __restrict__ A,
                                                const float* __restrict__ Dp,
                                                unsigned short* __restrict__ xaug,
                                                unsigned short* __restrict__ As,
                                                unsigned short* __restrict__ Ast) {
  int b = blockIdx.x, tid = threadIdx.x;
  if (b < 1024) {
    int k = b >> 3, dc = b & 7;
    __shared__ float siDs[64];
    __shared__ unsigned short Tr[64][72];
    if (tid < 64) siDs[tid] = 1.0f / Dp[k * DF + dc * 64 + tid];
    __syncthreads();
#pragma unroll
    for (int q = 0; q < 4; ++q) {
      int f = q * 256 + tid;
      int dd = f >> 4, i4 = (f & 15) * 4;
      float4 v = *reinterpret_cast<const float4*>(&A[((size_t)(k * DF + dc * 64 + dd)) * LF + i4]);
      float s = siDs[dd];
      ushort4 u;
      u.x = bfr(v.x * s); u.y = bfr(v.y * s); u.z = bfr(v.z * s); u.w = bfr(v.w * s);
      *reinterpret_cast<ushort4*>(&As[((size_t)(k * DF + dc * 64 + dd)) * LF + i4]) = u;
      *reinterpret_cast<ushort4*>(&Tr[dd][i4]) = u;
    }
    __syncthreads();
    int i = tid >> 2, ds0 = (tid & 3) * 16;
    unsigned short t16[16];
#pragma unroll
    for (int e = 0; e < 16; ++e) t16[e] = Tr[ds0 + e][i];
    uint4 v0, v1;
    v0.x = (unsigned)t16[0] | ((unsigned)t16[1] << 16);
    v0.y = (unsigned)t16[2] | ((unsigned)t16[3] << 16);
    v0.z = (unsigned)t16[4] | ((unsigned)t16[5] << 16);
    v0.w = (unsigned)t16[6] | ((unsigned)t16[7] << 16);
    v1.x = (unsigned)t16[8] | ((unsigned)t16[9] << 16);
    v1.y = (unsigned)t16[10] | ((unsigned)t16[11] << 16);
    v1.z = (unsigned)t16[12] | ((unsigned)t16[13] << 16);
    v1.w = (unsigned)t16[14] | ((unsigned)t16[15] << 16);
    size_t ro = ((size_t)(k * LF + i)) * DF + dc * 64 + ds0;
    *reinterpret_cast<uint4*>(&Ast[ro]) = v0;
    *reinterpret_cast<uint4*>(&Ast[ro + 8]) = v1;
  } else {
    int f = (b - 1024) * 256 + tid;      // float4 index over NN*DF/4
    float4 v = reinterpret_cast<const float4*>(x)[f];
    int n = f >> 7, c4 = (f & 127) << 2;
    ushort4 a, s;
    a.x = bfr(v.x); a.y = bfr(v.y); a.z = bfr(v.z); a.w = bfr(v.w);
    s.x = bfr(v.x * v.x); s.y = bfr(v.y * v.y); s.z = bfr(v.z * v.z); s.w = bfr(v.w * v.w);
    *reinterpret_cast<ushort4*>(&xaug[(size_t)n * 1024 + c4]) = a;
    *reinterpret_cast<ushort4*>(&xaug[(size_t)n * 1024 + 512 + c4]) = s;
  }
}

// ============ PERCOMP: per k — stats, L syrk + fused m2, chol, Winv, h, c0, Wb ============
__global__ __launch_bounds__(256, 1) void mfa_percomp(const float* __restrict__ MU,
                                                      const float* __restrict__ Dp,
                                                      const float* __restrict__ PI,
                                                      const unsigned short* __restrict__ Ast,
                                                      unsigned short* __restrict__ Waug,
                                                      unsigned short* __restrict__ Wb,
                                                      float* __restrict__ hws,
                                                      float* __restrict__ c0g) {
  int k = blockIdx.x, tid = threadIdx.x, lane = tid & 63, w = tid >> 6;
  __shared__ unsigned short Tile[64 * 64];
  __shared__ float Cm[64 * 65];
  __shared__ float smuS[DF];
  __shared__ float m2part[256];
  __shared__ float m2S[64];
  __shared__ float invd_s[64];
  __shared__ float redq[80];
  __shared__ float c0a_s;

  // ---- phase B: stats, smu, Waug (first: smu needed by fused m2) ----
  {
    float slog = 0.f, smu2 = 0.f;
#pragma unroll
    for (int p = 0; p < 2; ++p) {
      int d = p * 256 + tid;
      float Dv = Dp[k * DF + d];
      float id = 1.f / (Dv * Dv);
      float mu = MU[k * DF + d];
      float wv = id * mu;
      smuS[d] = mu / Dv;
      Waug[(size_t)k * 1024 + d] = bfr(wv);
      Waug[(size_t)k * 1024 + 512 + d] = bfr(-0.5f * id);
      slog += logf(id);
      smu2 += wv * mu;
    }
#pragma unroll
    for (int m = 1; m < 64; m <<= 1) {
      slog += __shfl_xor(slog, m, 64);
      smu2 += __shfl_xor(smu2, m, 64);
    }
    if (lane == 0) { redq[w] = slog; redq[8 + w] = smu2; }
  }
  __syncthreads();
  if (tid == 0) {
    float sl = 0.f, sm = 0.f;
    for (int q = 0; q < 4; ++q) { sl += redq[q]; sm += redq[8 + q]; }
    c0a_s = PI[k] - 0.5f * (DF * 1.8378770664093453f + sm - sl);
  }

  // ---- phase A: L = Ast Ast^T via bf16 MFMA (K=512) + fused m2 partials ----
  f32x4 accL[4];
  f32x4 zero = {0.f, 0.f, 0.f, 0.f};
#pragma unroll
  for (int nj = 0; nj < 4; ++nj) accL[nj] = zero;
  int lr = lane >> 3, lc = lane & 7;
  int gcs = (lc ^ lr) * 8;
  float m2acc = 0.f;
  int mi_i = tid & 63, mi_g = tid >> 6;   // m2: thread -> (row i, d-group of 16)
  for (int kt = 0; kt < 8; ++kt) {
#pragma unroll
    for (int it = 0; it < 2; ++it) {
      int row = w * 8 + it * 32 + lr;
      ldst16(&Tile[(w * 8 + it * 32) * 64], Ast + ((size_t)(k * LF + row)) * DF + kt * 64 + gcs);
    }
    __syncthreads();
#pragma unroll
    for (int kk = 0; kk < 2; ++kk) {
      int sw = ((kk * 4 + (lane >> 4)) ^ (lane & 7)) * 8;
      short8 av = *reinterpret_cast<const short8*>(&Tile[(w * 16 + (lane & 15)) * 64 + sw]);
#pragma unroll
      for (int nj = 0; nj < 4; ++nj) {
        short8 bv = *reinterpret_cast<const short8*>(&Tile[(nj * 16 + (lane & 15)) * 64 + sw]);
        accL[nj] = __builtin_amdgcn_mfma_f32_16x16x32_bf16(av, bv, accL[nj], 0, 0, 0);
      }
    }
    // fused m2: Tile row mi_i, local d in [mi_g*16, mi_g*16+16); swizzled chunks
#pragma unroll
    for (int c2 = 0; c2 < 2; ++c2) {
      int g = mi_g * 2 + c2;                 // global chunk of 8 d
      int slot = g ^ (mi_i & 7);
      const unsigned* cp = reinterpret_cast<const unsigned*>(&Tile[mi_i * 64 + slot * 8]);
#pragma unroll
      for (int u2 = 0; u2 < 4; ++u2) {
        unsigned uu = cp[u2];
        int d0 = kt * 64 + g * 8 + u2 * 2;
        m2acc += b2f((unsigned short)(uu & 0xFFFF)) * smuS[d0];
        m2acc += b2f((unsigned short)(uu >> 16)) * smuS[d0 + 1];
      }
    }
    __syncthreads();
  }
#pragma unroll
  for (int nj = 0; nj < 4; ++nj)
#pragma unroll
    for (int reg = 0; reg < 4; ++reg) {
      int m = w * 16 + (lane >> 4) * 4 + reg;
      int n = nj * 16 + (lane & 15);
      Cm[m * 65 + n] = accL[nj][reg] + (m == n ? 1.f : 0.f);
    }
  m2part[tid] = m2acc;
  __syncthreads();
  if (tid < 64) m2S[tid] = m2part[tid] + m2part[tid + 64] + m2part[tid + 128] + m2part[tid + 192];

  // ---- phase D: scale-free right-looking Cholesky (diag raw) ----
  int tr = tid >> 4, tc = tid & 15;
  for (int j = 0; j < 64; ++j) {
    __syncthreads();
    float rinv = 1.0f / Cm[j * 65 + j];
#pragma unroll
    for (int a = 0; a < 4; ++a) {
      int r = j + 1 + tr + 16 * a;
      if (r < 64) {
        float crj = Cm[r * 65 + j] * rinv;
#pragma unroll
        for (int bb = 0; bb < 4; ++bb) {
          int c = j + 1 + tc + 16 * bb;
          if (c < 64) Cm[r * 65 + c] -= crj * Cm[c * 65 + j];
        }
      }
    }
  }
  __syncthreads();
  if (tid < 64) {
    float dg2 = Cm[tid * 65 + tid];
    invd_s[tid] = rsqrtf(dg2);
    redq[tid] = logf(dg2);
  }
  __syncthreads();
  if (tid == 0) {
    float s = 0.f;
    for (int q = 0; q < 64; ++q) s += redq[q];
    c0g[k] = c0a_s - 0.5f * s;
  }
  // ---- phase E: Winv (wave 0, column per lane, register recurrence, 4 accums) ----
  if (tid < 64) {
    int jc = tid;
    float w2[64];
#pragma unroll
    for (int r = 0; r < 64; ++r) {
      float s0 = (r == jc) ? 1.0f : 0.0f, s1 = 0.f, s2 = 0.f, s3 = 0.f;
      int i = 0;
#pragma unroll
      for (; i + 3 < r; i += 4) {
        s0 -= Cm[r * 65 + i] * w2[i];
        s1 -= Cm[r * 65 + i + 1] * w2[i + 1];
        s2 -= Cm[r * 65 + i + 2] * w2[i + 2];
        s3 -= Cm[r * 65 + i + 3] * w2[i + 3];
      }
#pragma unroll
      for (; i < r; ++i) s0 -= Cm[r * 65 + i] * w2[i];
      float idr = invd_s[r];
      float wr = ((s0 + s1) + (s2 + s3)) * idr;
      Cm[r * 65 + jc] = wr;
      w2[r] = wr * idr;
    }
  }
  // ---- phase F: h = Winv m2 ----
  if (tid < 64) {
    float hsum = 0.f;
#pragma unroll
    for (int j2 = 0; j2 < 64; ++j2) hsum += Cm[tid * 65 + j2] * m2S[j2];
    hws[k * 64 + tid] = hsum;
  }
  __syncthreads();
  // ---- phase G: Wb = bf16(Winv), row-major [l][i] ----
  {
    int l = tid >> 2, seg = (tid & 3) * 16;
    unsigned short t16[16];
#pragma unroll
    for (int e = 0; e < 16; ++e) t16[e] = bfr(Cm[l * 65 + seg + e]);
    uint4 v0, v1;
    v0.x = (unsigned)t16[0] | ((unsigned)t16[1] << 16);
    v0.y = (unsigned)t16[2] | ((unsigned)t16[3] << 16);
    v0.z = (unsigned)t16[4] | ((unsigned)t16[5] << 16);
    v0.w = (unsigned)t16[6] | ((unsigned)t16[7] << 16);
    v1.x = (unsigned)t16[8] | ((unsigned)t16[9] << 16);
    v1.y = (unsigned)t16[10] | ((unsigned)t16[11] << 16);
    v1.z = (unsigned)t16[12] | ((unsigned)t16[13] << 16);
    v1.w = (unsigned)t16[14] | ((unsigned)t16[15] << 16);
    size_t ro = ((size_t)(k * LF + l)) * LF + seg;
    *reinterpret_cast<uint4*>(&Wb[ro]) = v0;
    *reinterpret_cast<uint4*>(&Wb[ro + 8]) = v1;
  }
}

// ============ GT: Gt[l][d] = siD[d] * (Wb @ As^T), MFMA, per (k, d-quarter) ============
__global__ __launch_bounds__(256) void mfa_gt(const unsigned short* __restrict__ Wb,
                                              const unsigned short* __restrict__ As,
                                              const float* __restrict__ Dp,
                                              unsigned short* __restrict__ Gt) {
  int k = blockIdx.x, dq = blockIdx.y;
  int tid = threadIdx.x, lane = tid & 63, w = tid >> 6;
  __shared__ unsigned short Wbs[64 * 64];
  __shared__ unsigned short Ds[128 * 64];
  __shared__ unsigned short Cout[64][132];
  int lr = lane >> 3, lc = lane & 7;
  int gcs = (lc ^ lr) * 8;
#pragma unroll
  for (int it = 0; it < 2; ++it) {
    int row = w * 8 + it * 32 + lr;
    ldst16(&Wbs[(w * 8 + it * 32) * 64], Wb + ((size_t)(k * LF + row)) * LF + gcs);
  }
#pragma unroll
  for (int it = 0; it < 4; ++it) {
    int row = w * 8 + it * 32 + lr;
    ldst16(&Ds[(w * 8 + it * 32) * 64], As + ((size_t)(k * DF + dq * 128 + row)) * LF + gcs);
  }
  __syncthreads();
  f32x4 acc[4][2];
  f32x4 zero = {0.f, 0.f, 0.f, 0.f};
#pragma unroll
  for (int mi = 0; mi < 4; ++mi)
#pragma unroll
    for (int nj = 0; nj < 2; ++nj) acc[mi][nj] = zero;
#pragma unroll
  for (int kk = 0; kk < 2; ++kk) {
    int sw = ((kk * 4 + (lane >> 4)) ^ (lane & 7)) * 8;
    short8 av[4], bv[2];
#pragma unroll
    for (int mi = 0; mi < 4; ++mi)
      av[mi] = *reinterpret_cast<const short8*>(&Wbs[(mi * 16 + (lane & 15)) * 64 + sw]);
#pragma unroll
    for (int nj = 0; nj < 2; ++nj)
      bv[nj] = *reinterpret_cast<const short8*>(&Ds[(w * 32 + nj * 16 + (lane & 15)) * 64 + sw]);
#pragma unroll
    for (int mi = 0; mi < 4; ++mi)
#pragma unroll
      for (int nj = 0; nj < 2; ++nj)
        acc[mi][nj] = __builtin_amdgcn_mfma_f32_16x16x32_bf16(av[mi], bv[nj], acc[mi][nj], 0, 0, 0);
  }
  float siD[2];
#pragma unroll
  for (int nj = 0; nj < 2; ++nj)
    siD[nj] = 1.0f / Dp[k * DF + dq * 128 + w * 32 + nj * 16 + (lane & 15)];
#pragma unroll
  for (int mi = 0; mi < 4; ++mi)
#pragma unroll
    for (int nj = 0; nj < 2; ++nj) {
      int dl = w * 32 + nj * 16 + (lane & 15);
#pragma unroll
      for (int reg = 0; reg < 4; ++reg) {
        int l = mi * 16 + (lane >> 4) * 4 + reg;
        Cout[l][dl] = bfr(acc[mi][nj][reg] * siD[nj]);
      }
    }
  __syncthreads();
  {
    int l = tid >> 2, seg = (tid & 3) * 32;
    uint4* dst = reinterpret_cast<uint4*>(&Gt[((size_t)(k * LF + l)) * DF + dq * 128 + seg]);
#pragma unroll
    for (int u = 0; u < 4; ++u) {
      unsigned short t8[8];
#pragma unroll
      for (int e = 0; e < 8; ++e) t8[e] = Cout[l][seg + u * 8 + e];
      uint4 val;
      val.x = (unsigned)t8[0] | ((unsigned)t8[1] << 16);
      val.y = (unsigned)t8[2] | ((unsigned)t8[3] << 16);
      val.z = (unsigned)t8[4] | ((unsigned)t8[5] << 16);
      val.w = (unsigned)t8[6] | ((unsigned)t8[7] << 16);
      dst[u] = val;
    }
  }
}

// ============ Q1G: r12 partials = xaug(4096x1024) @ Waug^T(128x1024), K-split x4 ============
__global__ __launch_bounds__(256) void mfa_q1g(const unsigned short* __restrict__ xaug,
                                               const unsigned short* __restrict__ Waug,
                                               float* __restrict__ r12p) {
  int nb = blockIdx.x * 128, kq = blockIdx.y;
  int tid = threadIdx.x, lane = tid & 63, w = tid >> 6, wx = w & 1, wy = w >> 1;
  __shared__ unsigned short As[128 * 64];
  __shared__ unsigned short Bs[128 * 64];
  f32x4 acc[4][4];
  f32x4 zero = {0.f, 0.f, 0.f, 0.f};
#pragma unroll
  for (int mi = 0; mi < 4; ++mi)
#pragma unroll
    for (int nj = 0; nj < 4; ++nj) acc[mi][nj] = zero;
  const unsigned short* xg = xaug + (size_t)nb * 1024;
  int lr = lane >> 3, lc = lane & 7;
  int gcs = (lc ^ lr) * 8;
  for (int kt = 0; kt < 4; ++kt) {
    int kof = kq * 256 + kt * 64;
#pragma unroll
    for (int it = 0; it < 4; ++it) {
      int row = w * 8 + it * 32 + lr;
      ldst16(&As[(w * 8 + it * 32) * 64], xg + (size_t)row * 1024 + kof + gcs);
      ldst16(&Bs[(w * 8 + it * 32) * 64], Waug + (size_t)row * 1024 + kof + gcs);
    }
    __syncthreads();
#pragma unroll
    for (int kk = 0; kk < 2; ++kk) {
      int sw = ((kk * 4 + (lane >> 4)) ^ (lane & 7)) * 8;
      short8 av[4], bv[4];
#pragma unroll
      for (int mi = 0; mi < 4; ++mi)
        av[mi] = *reinterpret_cast<const short8*>(&As[(wy * 64 + mi * 16 + (lane & 15)) * 64 + sw]);
#pragma unroll
      for (int nj = 0; nj < 4; ++nj)
        bv[nj] = *reinterpret_cast<const short8*>(&Bs[(wx * 64 + nj * 16 + (lane & 15)) * 64 + sw]);
#pragma unroll
      for (int mi = 0; mi < 4; ++mi)
#pragma unroll
        for (int nj = 0; nj < 4; ++nj)
          acc[mi][nj] = __builtin_amdgcn_mfma_f32_16x16x32_bf16(av[mi], bv[nj], acc[mi][nj], 0, 0, 0);
    }
    __syncthreads();
  }
  float* outp = r12p + (size_t)kq * KC * NN;
#pragma unroll
  for (int mi = 0; mi < 4; ++mi)
#pragma unroll
    for (int nj = 0; nj < 4; ++nj) {
      int ccol = wx * 64 + nj * 16 + (lane & 15);
      int nrow = nb + wy * 64 + mi * 16 + (lane >> 4) * 4;
      float4 o;
      o.x = acc[mi][nj][0]; o.y = acc[mi][nj][1]; o.z = acc[mi][nj][2]; o.w = acc[mi][nj][3];
      *reinterpret_cast<float4*>(&outp[(size_t)ccol * NN + nrow]) = o;
    }
}

// ============ MAIN: x @ Gt^T + fused 0.5||u-h||^2 + c0 + r12 ============
__global__ __launch_bounds__(256) void mfa_main(const unsigned short* __restrict__ xaug,
                                                const unsigned short* __restrict__ Gt,
                                                const float* __restrict__ hws,
                                                const float* __restrict__ c0g,
                                                const float* __restrict__ r12p,
                                                float* __restrict__ s2b) {
  int bx = blockIdx.x, by = blockIdx.y;
  int tid = threadIdx.x, lane = tid & 63, w = tid >> 6, wx = w & 1, wy = w >> 1;
  __shared__ unsigned short As[128 * 64];
  __shared__ unsigned short Bs[128 * 64];
  f32x4 acc[4][4];
  f32x4 zero = {0.f, 0.f, 0.f, 0.f};
#pragma unroll
  for (int mi = 0; mi < 4; ++mi)
#pragma unroll
    for (int nj = 0; nj < 4; ++nj) acc[mi][nj] = zero;
  int nbase = by * 128, cbase = bx * 128;
  const unsigned short* xg = xaug + (size_t)nbase * 1024;
  const unsigned short* gg = Gt + (size_t)cbase * DF;
  int lr = lane >> 3, lc = lane & 7;
  int gcs = (lc ^ lr) * 8;
  for (int kt = 0; kt < 8; ++kt) {
#pragma unroll
    for (int it = 0; it < 4; ++it) {
      int row = w * 8 + it * 32 + lr;
      ldst16(&As[(w * 8 + it * 32) * 64], xg + (size_t)row * 1024 + kt * 64 + gcs);
      ldst16(&Bs[(w * 8 + it * 32) * 64], gg + (size_t)row * DF + kt * 64 + gcs);
    }
    __syncthreads();
#pragma unroll
    for (int kk = 0; kk < 2; ++kk) {
      int sw = ((kk * 4 + (lane >> 4)) ^ (lane & 7)) * 8;
      short8 av[4], bv[4];
#pragma unroll
      for (int mi = 0; mi < 4; ++mi)
        av[mi] = *reinterpret_cast<const short8*>(&As[(wy * 64 + mi * 16 + (lane & 15)) * 64 + sw]);
#pragma unroll
      for (int nj = 0; nj < 4; ++nj)
        bv[nj] = *reinterpret_cast<const short8*>(&Bs[(wx * 64 + nj * 16 + (lane & 15)) * 64 + sw]);
#pragma unroll
      for (int mi = 0; mi < 4; ++mi)
#pragma unroll
        for (int nj = 0; nj < 4; ++nj)
          acc[mi][nj] = __builtin_amdgcn_mfma_f32_16x16x32_bf16(av[mi], bv[nj], acc[mi][nj], 0, 0, 0);
    }
    __syncthreads();
  }
  int comp = bx * 2 + wx;
  float hv[4];
#pragma unroll
  for (int nj = 0; nj < 4; ++nj) hv[nj] = hws[comp * 64 + nj * 16 + (lane & 15)];
  float cc = c0g[comp];
  int rbase = nbase + wy * 64;
#pragma unroll
  for (int mi = 0; mi < 4; ++mi) {
    f32x4 sv;
#pragma unroll
    for (int reg = 0; reg < 4; ++reg) {
      float s = 0.f;
#pragma unroll
      for (int nj = 0; nj < 4; ++nj) {
        float dlt = acc[mi][nj][reg] - hv[nj];
        s += dlt * dlt;
      }
      s += __shfl_xor(s, 1, 64);
      s += __shfl_xor(s, 2, 64);
      s += __shfl_xor(s, 4, 64);
      s += __shfl_xor(s, 8, 64);
      sv[reg] = s;
    }
    if ((lane & 15) == 0) {
      int nr = rbase + mi * 16 + (lane >> 4) * 4;
      size_t idx = (size_t)comp * NN + nr;
      float4 r0 = *reinterpret_cast<const float4*>(&r12p[idx]);
      float4 r1 = *reinterpret_cast<const float4*>(&r12p[(size_t)KC * NN + idx]);
      float4 r2 = *reinterpret_cast<const float4*>(&r12p[(size_t)2 * KC * NN + idx]);
      float4 r3 = *reinterpret_cast<const float4*>(&r12p[(size_t)3 * KC * NN + idx]);
      float4 o;
      o.x = 0.5f * sv[0] + cc + r0.x + r1.x + r2.x + r3.x;
      o.y = 0.5f * sv[1] + cc + r0.y + r1.y + r2.y + r3.y;
      o.z = 0.5f * sv[2] + cc + r0.z + r1.z + r2.z + r3.z;
      o.w = 0.5f * sv[3] + cc + r0.w + r1.w + r2.w + r3.w;
      *reinterpret_cast<float4*>(&s2b[idx]) = o;
    }
  }
}

// ============ LSE over K ============
__global__ __launch_bounds__(64) void mfa_lse(const float* __restrict__ s2b,
                                              float* __restrict__ out) {
  int n = blockIdx.x * 64 + threadIdx.x;
  float m = -3.0e38f, s = 0.f;
#pragma unroll 8
  for (int k = 0; k < KC; ++k) {
    float t = s2b[(size_t)k * NN + n];
    float nm = fmaxf(m, t);
    s = s * expf(m - nm) + expf(t - nm);
    m = nm;
  }
  out[n] = m + logf(s);
}

extern "C" void kernel_launch(void* const* d_in, const int* in_sizes, int n_in,
                              void* d_out, int out_size, void* d_ws, size_t ws_size,
                              hipStream_t stream) {
  const float* x  = (const float*)d_in[0];
  const float* MU = (const float*)d_in[1];
  const float* A  = (const float*)d_in[2];
  const float* Dp = (const float*)d_in[3];
  const float* PI = (const float*)d_in[4];
  float* out = (float*)d_out;

  char* base = (char*)d_ws;
  size_t off = 0;
  auto alloc = [&](size_t bytes) -> void* {
    void* p = base + off;
    off += (bytes + 255) & ~(size_t)255;
    return p;
  };
  unsigned short* xaug = (unsigned short*)alloc((size_t)NN * 1024 * 2);    // 16 MB
  unsigned short* As   = (unsigned short*)alloc((size_t)KC * DF * LF * 2); // 8 MB
  unsigned short* Ast  = (unsigned short*)alloc((size_t)KC * LF * DF * 2); // 8 MB
  unsigned short* Waug = (unsigned short*)alloc((size_t)KC * 1024 * 2);    // 256 KB
  unsigned short* Wb   = (unsigned short*)alloc((size_t)KC * LF * LF * 2); // 1 MB
  unsigned short* Gt   = (unsigned short*)alloc((size_t)KC * LF * DF * 2); // 8 MB
  float* hws           = (float*)alloc((size_t)KC * 64 * 4);
  float* c0g           = (float*)alloc((size_t)KC * 4);
  float* r12p          = (float*)alloc((size_t)4 * KC * NN * 4);           // 8 MB
  float* s2b           = (float*)alloc((size_t)KC * NN * 4);               // 2 MB

  mfa_prep<<<3072, 256, 0, stream>>>(x, A, Dp, xaug, As, Ast);
  mfa_percomp<<<KC, 256, 0, stream>>>(MU, Dp, PI, Ast, Waug, Wb, hws, c0g);
  mfa_gt<<<dim3(KC, 4), 256, 0, stream>>>(Wb, As, Dp, Gt);
  mfa_q1g<<<dim3(NN / 128, 4), 256, 0, stream>>>(xaug, Waug, r12p);
  mfa_main<<<dim3(64, NN / 128), 256, 0, stream>>>(xaug, Gt, hws, c0g, r12p, s2b);
  mfa_lse<<<NN / 64, 64, 0, stream>>>(s2b, out);
}

// Round 7
// 200.672 us; speedup vs baseline: 1.4158x; 1.0662x over previous
//
#include <hip/hip_runtime.h>
#include <math.h>

// MFA Woodbury log-likelihood:
//   per_comp[k,n] = c0_k + x.w_k - 0.5*x^2.iD_k + 0.5*||G_k^T x - h_k||^2
//   out[n] = logsumexp_k per_comp[k,n]
// As = sqrt(iD) .* A (bf16); L = As^T As + I = C C^T; Winv = C^{-1} (bf16 Wb)
// Gt = sqrt(iD) .* (Winv As^T); h = Winv (As^T smu), smu = sqrt(iD)*mu
// percomp computes Winv via AUGMENTED elimination: chol + unit-inverse in one
// 64-iteration loop (Xu = L_unit^{-1}; Winv = diag(rsqrt(d)) Xu) — no per-lane
// serial recurrence, no scratch arrays.
// 6 dispatches: prep, percomp, gt, q1g, main, lse.

#define KC 128
#define DF 512
#define LF 64
#define NN 4096

typedef __attribute__((ext_vector_type(8))) short short8;
typedef __attribute__((ext_vector_type(4))) float f32x4;

static __device__ __forceinline__ unsigned short bfr(float f) {
  union { float f; unsigned u; } v; v.f = f;
  return (unsigned short)((v.u + 0x7FFFu + ((v.u >> 16) & 1u)) >> 16);
}
static __device__ __forceinline__ float b2f(unsigned short u) {
  union { unsigned u; float f; } v; v.u = ((unsigned)u) << 16; return v.f;
}
static __device__ __forceinline__ void ldst16(void* lds, const void* g) {
  __builtin_amdgcn_global_load_lds((const __attribute__((address_space(1))) void*)g,
                                   (__attribute__((address_space(3))) void*)lds,
                                   16, 0, 0);
}

// ============ PREP: x -> xaug=[x|x^2] bf16 ; A -> As (d-major) + Ast (i-major) ============
__global__ __launch_bounds__(256) void mfa_prep(const float* __restrict__ x,
                                                const float* __restrict__ A,
                                                const float* __restrict__ Dp,
                                                unsigned short* __restrict__ xaug,
                                                unsigned short* __restrict__ As,
                                                unsigned short* __restrict__ Ast) {
  int b = blockIdx.x, tid = threadIdx.x;
  if (b < 1024) {
    int k = b >> 3, dc = b & 7;
    __shared__ float siDs[64];
    __shared__ unsigned short Tr[64][72];
    if (tid < 64) siDs[tid] = 1.0f / Dp[k * DF + dc * 64 + tid];
    __syncthreads();
#pragma unroll
    for (int q = 0; q < 4; ++q) {
      int f = q * 256 + tid;
      int dd = f >> 4, i4 = (f & 15) * 4;
      float4 v = *reinterpret_cast<const float4*>(&A[((size_t)(k * DF + dc * 64 + dd)) * LF + i4]);
      float s = siDs[dd];
      ushort4 u;
      u.x = bfr(v.x * s); u.y = bfr(v.y * s); u.z = bfr(v.z * s); u.w = bfr(v.w * s);
      *reinterpret_cast<ushort4*>(&As[((size_t)(k * DF + dc * 64 + dd)) * LF + i4]) = u;
      *reinterpret_cast<ushort4*>(&Tr[dd][i4]) = u;
    }
    __syncthreads();
    int i = tid >> 2, ds0 = (tid & 3) * 16;
    unsigned short t16[16];
#pragma unroll
    for (int e = 0; e < 16; ++e) t16[e] = Tr[ds0 + e][i];
    uint4 v0, v1;
    v0.x = (unsigned)t16[0] | ((unsigned)t16[1] << 16);
    v0.y = (unsigned)t16[2] | ((unsigned)t16[3] << 16);
    v0.z = (unsigned)t16[4] | ((unsigned)t16[5] << 16);
    v0.w = (unsigned)t16[6] | ((unsigned)t16[7] << 16);
    v1.x = (unsigned)t16[8] | ((unsigned)t16[9] << 16);
    v1.y = (unsigned)t16[10] | ((unsigned)t16[11] << 16);
    v1.z = (unsigned)t16[12] | ((unsigned)t16[13] << 16);
    v1.w = (unsigned)t16[14] | ((unsigned)t16[15] << 16);
    size_t ro = ((size_t)(k * LF + i)) * DF + dc * 64 + ds0;
    *reinterpret_cast<uint4*>(&Ast[ro]) = v0;
    *reinterpret_cast<uint4*>(&Ast[ro + 8]) = v1;
  } else {
    int f = (b - 1024) * 256 + tid;      // float4 index over NN*DF/4
    float4 v = reinterpret_cast<const float4*>(x)[f];
    int n = f >> 7, c4 = (f & 127) << 2;
    ushort4 a, s;
    a.x = bfr(v.x); a.y = bfr(v.y); a.z = bfr(v.z); a.w = bfr(v.w);
    s.x = bfr(v.x * v.x); s.y = bfr(v.y * v.y); s.z = bfr(v.z * v.z); s.w = bfr(v.w * v.w);
    *reinterpret_cast<ushort4*>(&xaug[(size_t)n * 1024 + c4]) = a;
    *reinterpret_cast<ushort4*>(&xaug[(size_t)n * 1024 + 512 + c4]) = s;
  }
}

// ============ PERCOMP: per k — stats, L syrk + fused m2, augmented chol+inverse, h, c0, Wb ============
__global__ __launch_bounds__(256) void mfa_percomp(const float* __restrict__ MU,
                                                   const float* __restrict__ Dp,
                                                   const float* __restrict__ PI,
                                                   const unsigned short* __restrict__ Ast,
                                                   unsigned short* __restrict__ Waug,
                                                   unsigned short* __restrict__ Wb,
                                                   float* __restrict__ hws,
                                                   float* __restrict__ c0g) {
  int k = blockIdx.x, tid = threadIdx.x, lane = tid & 63, w = tid >> 6;
  __shared__ unsigned short Tile[64 * 64];
  __shared__ float Cm[64 * 65];
  __shared__ float Xu[64 * 65];
  __shared__ float smuS[DF];
  __shared__ float m2part[256];
  __shared__ float m2S[64];
  __shared__ float invd_s[64];
  __shared__ float redq[80];
  __shared__ float c0a_s;

  // ---- init Xu = I ----
  for (int idx = tid; idx < 4096; idx += 256) {
    int r = idx >> 6, c = idx & 63;
    Xu[r * 65 + c] = (r == c) ? 1.f : 0.f;
  }

  // ---- phase B: stats, smu, Waug ----
  {
    float slog = 0.f, smu2 = 0.f;
#pragma unroll
    for (int p = 0; p < 2; ++p) {
      int d = p * 256 + tid;
      float Dv = Dp[k * DF + d];
      float id = 1.f / (Dv * Dv);
      float mu = MU[k * DF + d];
      float wv = id * mu;
      smuS[d] = mu / Dv;
      Waug[(size_t)k * 1024 + d] = bfr(wv);
      Waug[(size_t)k * 1024 + 512 + d] = bfr(-0.5f * id);
      slog += logf(id);
      smu2 += wv * mu;
    }
#pragma unroll
    for (int m = 1; m < 64; m <<= 1) {
      slog += __shfl_xor(slog, m, 64);
      smu2 += __shfl_xor(smu2, m, 64);
    }
    if (lane == 0) { redq[w] = slog; redq[8 + w] = smu2; }
  }
  __syncthreads();
  if (tid == 0) {
    float sl = 0.f, sm = 0.f;
    for (int q = 0; q < 4; ++q) { sl += redq[q]; sm += redq[8 + q]; }
    c0a_s = PI[k] - 0.5f * (DF * 1.8378770664093453f + sm - sl);
  }

  // ---- phase A: L = Ast Ast^T via bf16 MFMA (K=512) + fused m2 partials ----
  f32x4 accL[4];
  f32x4 zero = {0.f, 0.f, 0.f, 0.f};
#pragma unroll
  for (int nj = 0; nj < 4; ++nj) accL[nj] = zero;
  int lr = lane >> 3, lc = lane & 7;
  int gcs = (lc ^ lr) * 8;
  float m2acc = 0.f;
  int mi_i = tid & 63, mi_g = tid >> 6;   // m2: thread -> (row i, d-group of 16)
  for (int kt = 0; kt < 8; ++kt) {
#pragma unroll
    for (int it = 0; it < 2; ++it) {
      int row = w * 8 + it * 32 + lr;
      ldst16(&Tile[(w * 8 + it * 32) * 64], Ast + ((size_t)(k * LF + row)) * DF + kt * 64 + gcs);
    }
    __syncthreads();
#pragma unroll
    for (int kk = 0; kk < 2; ++kk) {
      int sw = ((kk * 4 + (lane >> 4)) ^ (lane & 7)) * 8;
      short8 av = *reinterpret_cast<const short8*>(&Tile[(w * 16 + (lane & 15)) * 64 + sw]);
#pragma unroll
      for (int nj = 0; nj < 4; ++nj) {
        short8 bv = *reinterpret_cast<const short8*>(&Tile[(nj * 16 + (lane & 15)) * 64 + sw]);
        accL[nj] = __builtin_amdgcn_mfma_f32_16x16x32_bf16(av, bv, accL[nj], 0, 0, 0);
      }
    }
    // fused m2: Tile row mi_i, local d in [mi_g*16, mi_g*16+16); swizzled chunks
#pragma unroll
    for (int c2 = 0; c2 < 2; ++c2) {
      int g = mi_g * 2 + c2;                 // global chunk of 8 d
      int slot = g ^ (mi_i & 7);
      const unsigned* cp = reinterpret_cast<const unsigned*>(&Tile[mi_i * 64 + slot * 8]);
#pragma unroll
      for (int u2 = 0; u2 < 4; ++u2) {
        unsigned uu = cp[u2];
        int d0 = kt * 64 + g * 8 + u2 * 2;
        m2acc += b2f((unsigned short)(uu & 0xFFFF)) * smuS[d0];
        m2acc += b2f((unsigned short)(uu >> 16)) * smuS[d0 + 1];
      }
    }
    __syncthreads();
  }
#pragma unroll
  for (int nj = 0; nj < 4; ++nj)
#pragma unroll
    for (int reg = 0; reg < 4; ++reg) {
      int m = w * 16 + (lane >> 4) * 4 + reg;
      int n = nj * 16 + (lane & 15);
      Cm[m * 65 + n] = accL[nj][reg] + (m == n ? 1.f : 0.f);
    }
  m2part[tid] = m2acc;
  __syncthreads();
  if (tid < 64) m2S[tid] = m2part[tid] + m2part[tid + 64] + m2part[tid + 128] + m2part[tid + 192];

  // ---- phase D: augmented elimination — chol (c>j) + unit-inverse Xu (c<=j) ----
  // Per iter j, multiplier crj = Cm[r][j]/Cm[j][j] updates both halves; 64
  // column-slots exactly cover {chol: j+1..63} ∪ {Xu: 0..j}. After the loop:
  // Xu = L_unit^{-1}; true Winv[r][c] = rsqrt(diag_r) * Xu[r][c].
  int tr = tid >> 4, tc = tid & 15;
  for (int j = 0; j < 64; ++j) {
    __syncthreads();
    float rinv = 1.0f / Cm[j * 65 + j];
#pragma unroll
    for (int a = 0; a < 4; ++a) {
      int r = j + 1 + tr + 16 * a;
      if (r < 64) {
        float crj = Cm[r * 65 + j] * rinv;
#pragma unroll
        for (int bb = 0; bb < 4; ++bb) {
          int c = tc + 16 * bb;
          if (c > j) Cm[r * 65 + c] -= crj * Cm[c * 65 + j];
          else       Xu[r * 65 + c] -= crj * Xu[j * 65 + c];
        }
      }
    }
  }
  __syncthreads();
  if (tid < 64) {
    float dg2 = Cm[tid * 65 + tid];   // raw diag, untouched after iter tid
    invd_s[tid] = rsqrtf(dg2);
    redq[tid] = logf(dg2);
  }
  __syncthreads();
  if (tid == 0) {
    float s = 0.f;
    for (int q = 0; q < 64; ++q) s += redq[q];
    c0g[k] = c0a_s - 0.5f * s;
  }
  // ---- phase F: h = Winv m2 = diag(invd) Xu m2 ----
  if (tid < 64) {
    float hsum = 0.f;
#pragma unroll
    for (int j2 = 0; j2 < 64; ++j2) hsum += Xu[tid * 65 + j2] * m2S[j2];
    hws[k * 64 + tid] = hsum * invd_s[tid];
  }
  __syncthreads();
  // ---- phase G: Wb[l][i] = bf16(invd_l * Xu[l][i]) ----
  {
    int l = tid >> 2, seg = (tid & 3) * 16;
    float il = invd_s[l];
    unsigned short t16[16];
#pragma unroll
    for (int e = 0; e < 16; ++e) t16[e] = bfr(il * Xu[l * 65 + seg + e]);
    uint4 v0, v1;
    v0.x = (unsigned)t16[0] | ((unsigned)t16[1] << 16);
    v0.y = (unsigned)t16[2] | ((unsigned)t16[3] << 16);
    v0.z = (unsigned)t16[4] | ((unsigned)t16[5] << 16);
    v0.w = (unsigned)t16[6] | ((unsigned)t16[7] << 16);
    v1.x = (unsigned)t16[8] | ((unsigned)t16[9] << 16);
    v1.y = (unsigned)t16[10] | ((unsigned)t16[11] << 16);
    v1.z = (unsigned)t16[12] | ((unsigned)t16[13] << 16);
    v1.w = (unsigned)t16[14] | ((unsigned)t16[15] << 16);
    size_t ro = ((size_t)(k * LF + l)) * LF + seg;
    *reinterpret_cast<uint4*>(&Wb[ro]) = v0;
    *reinterpret_cast<uint4*>(&Wb[ro + 8]) = v1;
  }
}

// ============ GT: Gt[l][d] = siD[d] * (Wb @ As^T), MFMA, per (k, d-quarter) ============
__global__ __launch_bounds__(256) void mfa_gt(const unsigned short* __restrict__ Wb,
                                              const unsigned short* __restrict__ As,
                                              const float* __restrict__ Dp,
                                              unsigned short* __restrict__ Gt) {
  int k = blockIdx.x, dq = blockIdx.y;
  int tid = threadIdx.x, lane = tid & 63, w = tid >> 6;
  __shared__ unsigned short Wbs[64 * 64];
  __shared__ unsigned short Ds[128 * 64];
  __shared__ unsigned short Cout[64][132];
  int lr = lane >> 3, lc = lane & 7;
  int gcs = (lc ^ lr) * 8;
#pragma unroll
  for (int it = 0; it < 2; ++it) {
    int row = w * 8 + it * 32 + lr;
    ldst16(&Wbs[(w * 8 + it * 32) * 64], Wb + ((size_t)(k * LF + row)) * LF + gcs);
  }
#pragma unroll
  for (int it = 0; it < 4; ++it) {
    int row = w * 8 + it * 32 + lr;
    ldst16(&Ds[(w * 8 + it * 32) * 64], As + ((size_t)(k * DF + dq * 128 + row)) * LF + gcs);
  }
  __syncthreads();
  f32x4 acc[4][2];
  f32x4 zero = {0.f, 0.f, 0.f, 0.f};
#pragma unroll
  for (int mi = 0; mi < 4; ++mi)
#pragma unroll
    for (int nj = 0; nj < 2; ++nj) acc[mi][nj] = zero;
#pragma unroll
  for (int kk = 0; kk < 2; ++kk) {
    int sw = ((kk * 4 + (lane >> 4)) ^ (lane & 7)) * 8;
    short8 av[4], bv[2];
#pragma unroll
    for (int mi = 0; mi < 4; ++mi)
      av[mi] = *reinterpret_cast<const short8*>(&Wbs[(mi * 16 + (lane & 15)) * 64 + sw]);
#pragma unroll
    for (int nj = 0; nj < 2; ++nj)
      bv[nj] = *reinterpret_cast<const short8*>(&Ds[(w * 32 + nj * 16 + (lane & 15)) * 64 + sw]);
#pragma unroll
    for (int mi = 0; mi < 4; ++mi)
#pragma unroll
      for (int nj = 0; nj < 2; ++nj)
        acc[mi][nj] = __builtin_amdgcn_mfma_f32_16x16x32_bf16(av[mi], bv[nj], acc[mi][nj], 0, 0, 0);
  }
  float siD[2];
#pragma unroll
  for (int nj = 0; nj < 2; ++nj)
    siD[nj] = 1.0f / Dp[k * DF + dq * 128 + w * 32 + nj * 16 + (lane & 15)];
#pragma unroll
  for (int mi = 0; mi < 4; ++mi)
#pragma unroll
    for (int nj = 0; nj < 2; ++nj) {
      int dl = w * 32 + nj * 16 + (lane & 15);
#pragma unroll
      for (int reg = 0; reg < 4; ++reg) {
        int l = mi * 16 + (lane >> 4) * 4 + reg;
        Cout[l][dl] = bfr(acc[mi][nj][reg] * siD[nj]);
      }
    }
  __syncthreads();
  {
    int l = tid >> 2, seg = (tid & 3) * 32;
    uint4* dst = reinterpret_cast<uint4*>(&Gt[((size_t)(k * LF + l)) * DF + dq * 128 + seg]);
#pragma unroll
    for (int u = 0; u < 4; ++u) {
      unsigned short t8[8];
#pragma unroll
      for (int e = 0; e < 8; ++e) t8[e] = Cout[l][seg + u * 8 + e];
      uint4 val;
      val.x = (unsigned)t8[0] | ((unsigned)t8[1] << 16);
      val.y = (unsigned)t8[2] | ((unsigned)t8[3] << 16);
      val.z = (unsigned)t8[4] | ((unsigned)t8[5] << 16);
      val.w = (unsigned)t8[6] | ((unsigned)t8[7] << 16);
      dst[u] = val;
    }
  }
}

// ============ Q1G: r12 partials = xaug(4096x1024) @ Waug^T(128x1024), K-split x4 ============
__global__ __launch_bounds__(256) void mfa_q1g(const unsigned short* __restrict__ xaug,
                                               const unsigned short* __restrict__ Waug,
                                               float* __restrict__ r12p) {
  int nb = blockIdx.x * 128, kq = blockIdx.y;
  int tid = threadIdx.x, lane = tid & 63, w = tid >> 6, wx = w & 1, wy = w >> 1;
  __shared__ unsigned short As[128 * 64];
  __shared__ unsigned short Bs[128 * 64];
  f32x4 acc[4][4];
  f32x4 zero = {0.f, 0.f, 0.f, 0.f};
#pragma unroll
  for (int mi = 0; mi < 4; ++mi)
#pragma unroll
    for (int nj = 0; nj < 4; ++nj) acc[mi][nj] = zero;
  const unsigned short* xg = xaug + (size_t)nb * 1024;
  int lr = lane >> 3, lc = lane & 7;
  int gcs = (lc ^ lr) * 8;
  for (int kt = 0; kt < 4; ++kt) {
    int kof = kq * 256 + kt * 64;
#pragma unroll
    for (int it = 0; it < 4; ++it) {
      int row = w * 8 + it * 32 + lr;
      ldst16(&As[(w * 8 + it * 32) * 64], xg + (size_t)row * 1024 + kof + gcs);
      ldst16(&Bs[(w * 8 + it * 32) * 64], Waug + (size_t)row * 1024 + kof + gcs);
    }
    __syncthreads();
#pragma unroll
    for (int kk = 0; kk < 2; ++kk) {
      int sw = ((kk * 4 + (lane >> 4)) ^ (lane & 7)) * 8;
      short8 av[4], bv[4];
#pragma unroll
      for (int mi = 0; mi < 4; ++mi)
        av[mi] = *reinterpret_cast<const short8*>(&As[(wy * 64 + mi * 16 + (lane & 15)) * 64 + sw]);
#pragma unroll
      for (int nj = 0; nj < 4; ++nj)
        bv[nj] = *reinterpret_cast<const short8*>(&Bs[(wx * 64 + nj * 16 + (lane & 15)) * 64 + sw]);
#pragma unroll
      for (int mi = 0; mi < 4; ++mi)
#pragma unroll
        for (int nj = 0; nj < 4; ++nj)
          acc[mi][nj] = __builtin_amdgcn_mfma_f32_16x16x32_bf16(av[mi], bv[nj], acc[mi][nj], 0, 0, 0);
    }
    __syncthreads();
  }
  float* outp = r12p + (size_t)kq * KC * NN;
#pragma unroll
  for (int mi = 0; mi < 4; ++mi)
#pragma unroll
    for (int nj = 0; nj < 4; ++nj) {
      int ccol = wx * 64 + nj * 16 + (lane & 15);
      int nrow = nb + wy * 64 + mi * 16 + (lane >> 4) * 4;
      float4 o;
      o.x = acc[mi][nj][0]; o.y = acc[mi][nj][1]; o.z = acc[mi][nj][2]; o.w = acc[mi][nj][3];
      *reinterpret_cast<float4*>(&outp[(size_t)ccol * NN + nrow]) = o;
    }
}

// ============ MAIN: x @ Gt^T + fused 0.5||u-h||^2 + c0 + r12 ============
__global__ __launch_bounds__(256) void mfa_main(const unsigned short* __restrict__ xaug,
                                                const unsigned short* __restrict__ Gt,
                                                const float* __restrict__ hws,
                                                const float* __restrict__ c0g,
                                                const float* __restrict__ r12p,
                                                float* __restrict__ s2b) {
  int bx = blockIdx.x, by = blockIdx.y;
  int tid = threadIdx.x, lane = tid & 63, w = tid >> 6, wx = w & 1, wy = w >> 1;
  __shared__ unsigned short As[128 * 64];
  __shared__ unsigned short Bs[128 * 64];
  f32x4 acc[4][4];
  f32x4 zero = {0.f, 0.f, 0.f, 0.f};
#pragma unroll
  for (int mi = 0; mi < 4; ++mi)
#pragma unroll
    for (int nj = 0; nj < 4; ++nj) acc[mi][nj] = zero;
  int nbase = by * 128, cbase = bx * 128;
  const unsigned short* xg = xaug + (size_t)nbase * 1024;
  const unsigned short* gg = Gt + (size_t)cbase * DF;
  int lr = lane >> 3, lc = lane & 7;
  int gcs = (lc ^ lr) * 8;
  for (int kt = 0; kt < 8; ++kt) {
#pragma unroll
    for (int it = 0; it < 4; ++it) {
      int row = w * 8 + it * 32 + lr;
      ldst16(&As[(w * 8 + it * 32) * 64], xg + (size_t)row * 1024 + kt * 64 + gcs);
      ldst16(&Bs[(w * 8 + it * 32) * 64], gg + (size_t)row * DF + kt * 64 + gcs);
    }
    __syncthreads();
#pragma unroll
    for (int kk = 0; kk < 2; ++kk) {
      int sw = ((kk * 4 + (lane >> 4)) ^ (lane & 7)) * 8;
      short8 av[4], bv[4];
#pragma unroll
      for (int mi = 0; mi < 4; ++mi)
        av[mi] = *reinterpret_cast<const short8*>(&As[(wy * 64 + mi * 16 + (lane & 15)) * 64 + sw]);
#pragma unroll
      for (int nj = 0; nj < 4; ++nj)
        bv[nj] = *reinterpret_cast<const short8*>(&Bs[(wx * 64 + nj * 16 + (lane & 15)) * 64 + sw]);
#pragma unroll
      for (int mi = 0; mi < 4; ++mi)
#pragma unroll
        for (int nj = 0; nj < 4; ++nj)
          acc[mi][nj] = __builtin_amdgcn_mfma_f32_16x16x32_bf16(av[mi], bv[nj], acc[mi][nj], 0, 0, 0);
    }
    __syncthreads();
  }
  int comp = bx * 2 + wx;
  float hv[4];
#pragma unroll
  for (int nj = 0; nj < 4; ++nj) hv[nj] = hws[comp * 64 + nj * 16 + (lane & 15)];
  float cc = c0g[comp];
  int rbase = nbase + wy * 64;
#pragma unroll
  for (int mi = 0; mi < 4; ++mi) {
    f32x4 sv;
#pragma unroll
    for (int reg = 0; reg < 4; ++reg) {
      float s = 0.f;
#pragma unroll
      for (int nj = 0; nj < 4; ++nj) {
        float dlt = acc[mi][nj][reg] - hv[nj];
        s += dlt * dlt;
      }
      s += __shfl_xor(s, 1, 64);
      s += __shfl_xor(s, 2, 64);
      s += __shfl_xor(s, 4, 64);
      s += __shfl_xor(s, 8, 64);
      sv[reg] = s;
    }
    if ((lane & 15) == 0) {
      int nr = rbase + mi * 16 + (lane >> 4) * 4;
      size_t idx = (size_t)comp * NN + nr;
      float4 r0 = *reinterpret_cast<const float4*>(&r12p[idx]);
      float4 r1 = *reinterpret_cast<const float4*>(&r12p[(size_t)KC * NN + idx]);
      float4 r2 = *reinterpret_cast<const float4*>(&r12p[(size_t)2 * KC * NN + idx]);
      float4 r3 = *reinterpret_cast<const float4*>(&r12p[(size_t)3 * KC * NN + idx]);
      float4 o;
      o.x = 0.5f * sv[0] + cc + r0.x + r1.x + r2.x + r3.x;
      o.y = 0.5f * sv[1] + cc + r0.y + r1.y + r2.y + r3.y;
      o.z = 0.5f * sv[2] + cc + r0.z + r1.z + r2.z + r3.z;
      o.w = 0.5f * sv[3] + cc + r0.w + r1.w + r2.w + r3.w;
      *reinterpret_cast<float4*>(&s2b[idx]) = o;
    }
  }
}

// ============ LSE over K ============
__global__ __launch_bounds__(64) void mfa_lse(const float* __restrict__ s2b,
                                              float* __restrict__ out) {
  int n = blockIdx.x * 64 + threadIdx.x;
  float m = -3.0e38f, s = 0.f;
#pragma unroll 8
  for (int k = 0; k < KC; ++k) {
    float t = s2b[(size_t)k * NN + n];
    float nm = fmaxf(m, t);
    s = s * expf(m - nm) + expf(t - nm);
    m = nm;
  }
  out[n] = m + logf(s);
}

extern "C" void kernel_launch(void* const* d_in, const int* in_sizes, int n_in,
                              void* d_out, int out_size, void* d_ws, size_t ws_size,
                              hipStream_t stream) {
  const float* x  = (const float*)d_in[0];
  const float* MU = (const float*)d_in[1];
  const float* A  = (const float*)d_in[2];
  const float* Dp = (const float*)d_in[3];
  const float* PI = (const float*)d_in[4];
  float* out = (float*)d_out;

  char* base = (char*)d_ws;
  size_t off = 0;
  auto alloc = [&](size_t bytes) -> void* {
    void* p = base + off;
    off += (bytes + 255) & ~(size_t)255;
    return p;
  };
  unsigned short* xaug = (unsigned short*)alloc((size_t)NN * 1024 * 2);    // 16 MB
  unsigned short* As   = (unsigned short*)alloc((size_t)KC * DF * LF * 2); // 8 MB
  unsigned short* Ast  = (unsigned short*)alloc((size_t)KC * LF * DF * 2); // 8 MB
  unsigned short* Waug = (unsigned short*)alloc((size_t)KC * 1024 * 2);    // 256 KB
  unsigned short* Wb   = (unsigned short*)alloc((size_t)KC * LF * LF * 2); // 1 MB
  unsigned short* Gt   = (unsigned short*)alloc((size_t)KC * LF * DF * 2); // 8 MB
  float* hws           = (float*)alloc((size_t)KC * 64 * 4);
  float* c0g           = (float*)alloc((size_t)KC * 4);
  float* r12p          = (float*)alloc((size_t)4 * KC * NN * 4);           // 8 MB
  float* s2b           = (float*)alloc((size_t)KC * NN * 4);               // 2 MB

  mfa_prep<<<3072, 256, 0, stream>>>(x, A, Dp, xaug, As, Ast);
  mfa_percomp<<<KC, 256, 0, stream>>>(MU, Dp, PI, Ast, Waug, Wb, hws, c0g);
  mfa_gt<<<dim3(KC, 4), 256, 0, stream>>>(Wb, As, Dp, Gt);
  mfa_q1g<<<dim3(NN / 128, 4), 256, 0, stream>>>(xaug, Waug, r12p);
  mfa_main<<<dim3(64, NN / 128), 256, 0, stream>>>(xaug, Gt, hws, c0g, r12p, s2b);
  mfa_lse<<<NN / 64, 64, 0, stream>>>(s2b, out);
}

// Round 8
// 168.720 us; speedup vs baseline: 1.6839x; 1.1894x over previous
//
#include <hip/hip_runtime.h>
#include <math.h>

// MFA Woodbury log-likelihood:
//   per_comp[k,n] = c0_k + x.w_k - 0.5*x^2.iD_k + 0.5*||G_k^T x - h_k||^2
//   out[n] = logsumexp_k per_comp[k,n]
// As = sqrt(iD) .* A (bf16); L = As^T As + I; LDL^T via rank-4 blocked Gauss
// elimination on S=[L|I] -> [U | L_unit^{-1}]; Winv = diag(rsqrt(diag U)) Xu.
// Gt = sqrt(iD) .* (Winv As^T) fused into percomp (MFMA).
// 5 dispatches: prep, percomp(+gt), q1g, main, lse.

#define KC 128
#define DF 512
#define LF 64
#define NN 4096

typedef __attribute__((ext_vector_type(8))) short short8;
typedef __attribute__((ext_vector_type(4))) float f32x4;

static __device__ __forceinline__ unsigned short bfr(float f) {
  union { float f; unsigned u; } v; v.f = f;
  return (unsigned short)((v.u + 0x7FFFu + ((v.u >> 16) & 1u)) >> 16);
}
static __device__ __forceinline__ float b2f(unsigned short u) {
  union { unsigned u; float f; } v; v.u = ((unsigned)u) << 16; return v.f;
}
static __device__ __forceinline__ void ldst16(void* lds, const void* g) {
  __builtin_amdgcn_global_load_lds((const __attribute__((address_space(1))) void*)g,
                                   (__attribute__((address_space(3))) void*)lds,
                                   16, 0, 0);
}

// ============ PREP: x -> xaug=[x|x^2] bf16 ; A -> As (d-major) + Ast (i-major) ============
__global__ __launch_bounds__(256) void mfa_prep(const float* __restrict__ x,
                                                const float* __restrict__ A,
                                                const float* __restrict__ Dp,
                                                unsigned short* __restrict__ xaug,
                                                unsigned short* __restrict__ As,
                                                unsigned short* __restrict__ Ast) {
  int b = blockIdx.x, tid = threadIdx.x;
  if (b < 1024) {
    int k = b >> 3, dc = b & 7;
    __shared__ float siDs[64];
    __shared__ unsigned short Tr[64][72];
    if (tid < 64) siDs[tid] = 1.0f / Dp[k * DF + dc * 64 + tid];
    __syncthreads();
#pragma unroll
    for (int q = 0; q < 4; ++q) {
      int f = q * 256 + tid;
      int dd = f >> 4, i4 = (f & 15) * 4;
      float4 v = *reinterpret_cast<const float4*>(&A[((size_t)(k * DF + dc * 64 + dd)) * LF + i4]);
      float s = siDs[dd];
      ushort4 u;
      u.x = bfr(v.x * s); u.y = bfr(v.y * s); u.z = bfr(v.z * s); u.w = bfr(v.w * s);
      *reinterpret_cast<ushort4*>(&As[((size_t)(k * DF + dc * 64 + dd)) * LF + i4]) = u;
      *reinterpret_cast<ushort4*>(&Tr[dd][i4]) = u;
    }
    __syncthreads();
    int i = tid >> 2, ds0 = (tid & 3) * 16;
    unsigned short t16[16];
#pragma unroll
    for (int e = 0; e < 16; ++e) t16[e] = Tr[ds0 + e][i];
    uint4 v0, v1;
    v0.x = (unsigned)t16[0] | ((unsigned)t16[1] << 16);
    v0.y = (unsigned)t16[2] | ((unsigned)t16[3] << 16);
    v0.z = (unsigned)t16[4] | ((unsigned)t16[5] << 16);
    v0.w = (unsigned)t16[6] | ((unsigned)t16[7] << 16);
    v1.x = (unsigned)t16[8] | ((unsigned)t16[9] << 16);
    v1.y = (unsigned)t16[10] | ((unsigned)t16[11] << 16);
    v1.z = (unsigned)t16[12] | ((unsigned)t16[13] << 16);
    v1.w = (unsigned)t16[14] | ((unsigned)t16[15] << 16);
    size_t ro = ((size_t)(k * LF + i)) * DF + dc * 64 + ds0;
    *reinterpret_cast<uint4*>(&Ast[ro]) = v0;
    *reinterpret_cast<uint4*>(&Ast[ro + 8]) = v1;
  } else {
    int f = (b - 1024) * 256 + tid;      // float4 index over NN*DF/4
    float4 v = reinterpret_cast<const float4*>(x)[f];
    int n = f >> 7, c4 = (f & 127) << 2;
    ushort4 a, s;
    a.x = bfr(v.x); a.y = bfr(v.y); a.z = bfr(v.z); a.w = bfr(v.w);
    s.x = bfr(v.x * v.x); s.y = bfr(v.y * v.y); s.z = bfr(v.z * v.z); s.w = bfr(v.w * v.w);
    *reinterpret_cast<ushort4*>(&xaug[(size_t)n * 1024 + c4]) = a;
    *reinterpret_cast<ushort4*>(&xaug[(size_t)n * 1024 + 512 + c4]) = s;
  }
}

// ============ PERCOMP: per k — stats, syrk+m2, rank-4 blocked elimination, h, c0, Gt ============
__global__ __launch_bounds__(256) void mfa_percomp(const float* __restrict__ MU,
                                                   const float* __restrict__ Dp,
                                                   const float* __restrict__ PI,
                                                   const unsigned short* __restrict__ Ast,
                                                   const unsigned short* __restrict__ As,
                                                   unsigned short* __restrict__ Waug,
                                                   unsigned short* __restrict__ Gt,
                                                   float* __restrict__ hws,
                                                   float* __restrict__ c0g) {
  int k = blockIdx.x, tid = threadIdx.x, lane = tid & 63, w = tid >> 6;
  __shared__ float S[64 * 132];          // combined [L | Xu], stride 132
  __shared__ unsigned short Tile[64 * 64];  // syrk staging; later aliased as Wbs
  __shared__ float smuS[DF];
  __shared__ float m2part[256];
  __shared__ float m2S[64];
  __shared__ float invd_s[64];
  __shared__ float redq[80];
  __shared__ float c0a_s;

  // ---- init Xu = I (cols 64..127) ----
  for (int idx = tid; idx < 4096; idx += 256) {
    int r = idx >> 6, c = idx & 63;
    S[r * 132 + 64 + c] = (r == c) ? 1.f : 0.f;
  }

  // ---- phase B: stats, smu, Waug ----
  {
    float slog = 0.f, smu2 = 0.f;
#pragma unroll
    for (int p = 0; p < 2; ++p) {
      int d = p * 256 + tid;
      float Dv = Dp[k * DF + d];
      float id = 1.f / (Dv * Dv);
      float mu = MU[k * DF + d];
      float wv = id * mu;
      smuS[d] = mu / Dv;
      Waug[(size_t)k * 1024 + d] = bfr(wv);
      Waug[(size_t)k * 1024 + 512 + d] = bfr(-0.5f * id);
      slog += logf(id);
      smu2 += wv * mu;
    }
#pragma unroll
    for (int m = 1; m < 64; m <<= 1) {
      slog += __shfl_xor(slog, m, 64);
      smu2 += __shfl_xor(smu2, m, 64);
    }
    if (lane == 0) { redq[w] = slog; redq[8 + w] = smu2; }
  }
  __syncthreads();
  if (tid == 0) {
    float sl = 0.f, sm = 0.f;
    for (int q = 0; q < 4; ++q) { sl += redq[q]; sm += redq[8 + q]; }
    c0a_s = PI[k] - 0.5f * (DF * 1.8378770664093453f + sm - sl);
  }

  // ---- phase A: L = Ast Ast^T via bf16 MFMA (K=512) + fused m2 partials ----
  f32x4 accL[4];
  f32x4 zero = {0.f, 0.f, 0.f, 0.f};
#pragma unroll
  for (int nj = 0; nj < 4; ++nj) accL[nj] = zero;
  int lr = lane >> 3, lc = lane & 7;
  int gcs = (lc ^ lr) * 8;
  float m2acc = 0.f;
  int mi_i = tid & 63, mi_g = tid >> 6;
  for (int kt = 0; kt < 8; ++kt) {
#pragma unroll
    for (int it = 0; it < 2; ++it) {
      int row = w * 8 + it * 32 + lr;
      ldst16(&Tile[(w * 8 + it * 32) * 64], Ast + ((size_t)(k * LF + row)) * DF + kt * 64 + gcs);
    }
    __syncthreads();
#pragma unroll
    for (int kk = 0; kk < 2; ++kk) {
      int sw = ((kk * 4 + (lane >> 4)) ^ (lane & 7)) * 8;
      short8 av = *reinterpret_cast<const short8*>(&Tile[(w * 16 + (lane & 15)) * 64 + sw]);
#pragma unroll
      for (int nj = 0; nj < 4; ++nj) {
        short8 bv = *reinterpret_cast<const short8*>(&Tile[(nj * 16 + (lane & 15)) * 64 + sw]);
        accL[nj] = __builtin_amdgcn_mfma_f32_16x16x32_bf16(av, bv, accL[nj], 0, 0, 0);
      }
    }
#pragma unroll
    for (int c2 = 0; c2 < 2; ++c2) {
      int g = mi_g * 2 + c2;
      int slot = g ^ (mi_i & 7);
      const unsigned* cp = reinterpret_cast<const unsigned*>(&Tile[mi_i * 64 + slot * 8]);
#pragma unroll
      for (int u2 = 0; u2 < 4; ++u2) {
        unsigned uu = cp[u2];
        int d0 = kt * 64 + g * 8 + u2 * 2;
        m2acc += b2f((unsigned short)(uu & 0xFFFF)) * smuS[d0];
        m2acc += b2f((unsigned short)(uu >> 16)) * smuS[d0 + 1];
      }
    }
    __syncthreads();
  }
#pragma unroll
  for (int nj = 0; nj < 4; ++nj)
#pragma unroll
    for (int reg = 0; reg < 4; ++reg) {
      int m = w * 16 + (lane >> 4) * 4 + reg;
      int n = nj * 16 + (lane & 15);
      S[m * 132 + n] = accL[nj][reg] + (m == n ? 1.f : 0.f);
    }
  m2part[tid] = m2acc;
  __syncthreads();
  if (tid < 64) m2S[tid] = m2part[tid] + m2part[tid + 64] + m2part[tid + 128] + m2part[tid + 192];

  // ---- phase D: rank-4 blocked Gauss elimination on S=[L|I] ----
  // Invariant: at outer J (mult of 4), all rows updated through col J-1.
  // Active col window = [J+4, J+68) (64 cols). Panel rows J..J+3 are finalized
  // this step: block cols via redundant 4x4 elim, window cols via T-composed
  // coefficients (self-elimination multipliers masked to 0).
  {
    int rg = tid >> 4, cg = tid & 15;
    for (int Jo = 0; Jo < 16; ++Jo) {
      int J = Jo * 4;
      __syncthreads();
      // --- read phase (no writes) ---
      f32x4 B0 = *reinterpret_cast<f32x4*>(&S[(J + 0) * 132 + J]);
      f32x4 B1 = *reinterpret_cast<f32x4*>(&S[(J + 1) * 132 + J]);
      f32x4 B2 = *reinterpret_cast<f32x4*>(&S[(J + 2) * 132 + J]);
      f32x4 B3 = *reinterpret_cast<f32x4*>(&S[(J + 3) * 132 + J]);
      int cc = J + 4 + cg * 4;
      f32x4 S0 = *reinterpret_cast<f32x4*>(&S[(J + 0) * 132 + cc]);
      f32x4 S1 = *reinterpret_cast<f32x4*>(&S[(J + 1) * 132 + cc]);
      f32x4 S2 = *reinterpret_cast<f32x4*>(&S[(J + 2) * 132 + cc]);
      f32x4 S3 = *reinterpret_cast<f32x4*>(&S[(J + 3) * 132 + cc]);
      f32x4 V[4], TGT[4];
#pragma unroll
      for (int a = 0; a < 4; ++a) {
        int r = J + rg + 16 * a;
        if (r < 64) {
          V[a] = *reinterpret_cast<f32x4*>(&S[r * 132 + J]);
          TGT[a] = *reinterpret_cast<f32x4*>(&S[r * 132 + cc]);
        }
      }
      __syncthreads();
      // --- redundant 4x4 block elimination (LDL^T pivots, unit multipliers) ---
      float p0 = 1.0f / B0[0];
      float m10 = B1[0] * p0;  B1 -= m10 * B0;
      float m20 = B2[0] * p0;  B2 -= m20 * B0;
      float m30 = B3[0] * p0;  B3 -= m30 * B0;
      float p1 = 1.0f / B1[1];
      float m21 = B2[1] * p1;  B2 -= m21 * B1;
      float m31 = B3[1] * p1;  B3 -= m31 * B1;
      float p2 = 1.0f / B2[2];
      float m32 = B3[2] * p2;  B3 -= m32 * B2;
      float p3 = 1.0f / B3[3];
      // T rows: T_i = e_i - sum_{i'<i} m_{i,i'} T_{i'}
      float T1_0 = -m10;
      float T2_1 = -m21, T2_0 = -m20 - m21 * T1_0;
      float T3_2 = -m32, T3_1 = -m31 - m32 * T2_1, T3_0 = -m30 - m31 * T1_0 - m32 * T2_0;
      // panel block writes (final U block rows)
      if (cg == 0 && rg < 4) {
        f32x4 bw = (rg == 0) ? B0 : (rg == 1) ? B1 : (rg == 2) ? B2 : B3;
        *reinterpret_cast<f32x4*>(&S[(J + rg) * 132 + J]) = bw;
      }
      // --- window update ---
#pragma unroll
      for (int a = 0; a < 4; ++a) {
        int r = J + rg + 16 * a;
        if (r < 64) {
          f32x4 v = V[a];
          float n0 = v[0] * p0;
          float t1 = v[1] - n0 * B0[1];
          float n1 = t1 * p1;
          float t2 = v[2] - n0 * B0[2] - n1 * B1[2];
          float n2 = t2 * p2;
          float t3 = v[3] - n0 * B0[3] - n1 * B1[3] - n2 * B2[3];
          float n3 = t3 * p3;
          int pi = r - J;
          if (pi < 1) n0 = 0.f;
          if (pi < 2) n1 = 0.f;
          if (pi < 3) n2 = 0.f;
          if (pi < 4) n3 = 0.f;
          float cA = n0 + n1 * T1_0 + n2 * T2_0 + n3 * T3_0;
          float cB = n1 + n2 * T2_1 + n3 * T3_1;
          float cC = n2 + n3 * T3_2;
          float cD = n3;
          f32x4 res = TGT[a] - cA * S0 - cB * S1 - cC * S2 - cD * S3;
          *reinterpret_cast<f32x4*>(&S[r * 132 + cc]) = res;
        }
      }
    }
  }
  __syncthreads();
  // ---- diag, logdet, invd ----
  if (tid < 64) {
    float dg2 = S[tid * 132 + tid];
    invd_s[tid] = rsqrtf(dg2);
    redq[tid] = logf(dg2);
  }
  __syncthreads();
  if (tid == 0) {
    float s = 0.f;
    for (int q = 0; q < 64; ++q) s += redq[q];
    c0g[k] = c0a_s - 0.5f * s;
  }
  // ---- h = diag(invd) * (Xu m2) ----
  if (tid < 64) {
    float hsum = 0.f;
#pragma unroll
    for (int j2 = 0; j2 < 64; ++j2) hsum += S[tid * 132 + 64 + j2] * m2S[j2];
    hws[k * 64 + tid] = hsum * invd_s[tid];
  }
  // ---- phase H: build Wbs (bf16, swizzled chunk layout) from Xu ----
  unsigned short* Wbs = Tile;   // Tile dead after syrk
  {
    int l = tid >> 2;
#pragma unroll
    for (int q = 0; q < 2; ++q) {
      int sc = (tid & 3) * 2 + q;
      int gch = sc ^ (l & 7);
      float il = invd_s[l];
      unsigned short t8[8];
#pragma unroll
      for (int e = 0; e < 8; ++e) t8[e] = bfr(il * S[l * 132 + 64 + gch * 8 + e]);
      uint4 val;
      val.x = (unsigned)t8[0] | ((unsigned)t8[1] << 16);
      val.y = (unsigned)t8[2] | ((unsigned)t8[3] << 16);
      val.z = (unsigned)t8[4] | ((unsigned)t8[5] << 16);
      val.w = (unsigned)t8[6] | ((unsigned)t8[7] << 16);
      *reinterpret_cast<uint4*>(&Wbs[l * 64 + sc * 8]) = val;
    }
  }
  __syncthreads();   // S dead below: aliased by Ds/Cout
  // ---- phase I: Gt = siD .* (Wb @ As^T), 4 d-quarters, MFMA ----
  unsigned short* DsA = reinterpret_cast<unsigned short*>(S);          // 128*64 ush
  unsigned short* CoutA = reinterpret_cast<unsigned short*>(S) + 8192; // 64*132 ush
  for (int dq = 0; dq < 4; ++dq) {
#pragma unroll
    for (int it = 0; it < 4; ++it) {
      int row = w * 8 + it * 32 + lr;
      ldst16(&DsA[(w * 8 + it * 32) * 64], As + ((size_t)(k * DF + dq * 128 + row)) * LF + gcs);
    }
    __syncthreads();
    f32x4 gacc[4][2];
#pragma unroll
    for (int mi = 0; mi < 4; ++mi)
#pragma unroll
      for (int nj = 0; nj < 2; ++nj) gacc[mi][nj] = zero;
#pragma unroll
    for (int kk = 0; kk < 2; ++kk) {
      int sw = ((kk * 4 + (lane >> 4)) ^ (lane & 7)) * 8;
      short8 av[4], bv[2];
#pragma unroll
      for (int mi = 0; mi < 4; ++mi)
        av[mi] = *reinterpret_cast<const short8*>(&Wbs[(mi * 16 + (lane & 15)) * 64 + sw]);
#pragma unroll
      for (int nj = 0; nj < 2; ++nj)
        bv[nj] = *reinterpret_cast<const short8*>(&DsA[(w * 32 + nj * 16 + (lane & 15)) * 64 + sw]);
#pragma unroll
      for (int mi = 0; mi < 4; ++mi)
#pragma unroll
        for (int nj = 0; nj < 2; ++nj)
          gacc[mi][nj] = __builtin_amdgcn_mfma_f32_16x16x32_bf16(av[mi], bv[nj], gacc[mi][nj], 0, 0, 0);
    }
    float siD[2];
#pragma unroll
    for (int nj = 0; nj < 2; ++nj)
      siD[nj] = 1.0f / Dp[k * DF + dq * 128 + w * 32 + nj * 16 + (lane & 15)];
#pragma unroll
    for (int mi = 0; mi < 4; ++mi)
#pragma unroll
      for (int nj = 0; nj < 2; ++nj) {
        int dl = w * 32 + nj * 16 + (lane & 15);
#pragma unroll
        for (int reg = 0; reg < 4; ++reg) {
          int l = mi * 16 + (lane >> 4) * 4 + reg;
          CoutA[l * 132 + dl] = bfr(gacc[mi][nj][reg] * siD[nj]);
        }
      }
    __syncthreads();
    {
      int l = tid >> 2, seg = (tid & 3) * 32;
      uint4* dst = reinterpret_cast<uint4*>(&Gt[((size_t)(k * LF + l)) * DF + dq * 128 + seg]);
#pragma unroll
      for (int u = 0; u < 4; ++u) {
        unsigned short t8[8];
#pragma unroll
        for (int e = 0; e < 8; ++e) t8[e] = CoutA[l * 132 + seg + u * 8 + e];
        uint4 val;
        val.x = (unsigned)t8[0] | ((unsigned)t8[1] << 16);
        val.y = (unsigned)t8[2] | ((unsigned)t8[3] << 16);
        val.z = (unsigned)t8[4] | ((unsigned)t8[5] << 16);
        val.w = (unsigned)t8[6] | ((unsigned)t8[7] << 16);
        dst[u] = val;
      }
    }
    __syncthreads();
  }
}

// ============ Q1G: r12 partials = xaug(4096x1024) @ Waug^T(128x1024), K-split x4 ============
__global__ __launch_bounds__(256) void mfa_q1g(const unsigned short* __restrict__ xaug,
                                               const unsigned short* __restrict__ Waug,
                                               float* __restrict__ r12p) {
  int nb = blockIdx.x * 128, kq = blockIdx.y;
  int tid = threadIdx.x, lane = tid & 63, w = tid >> 6, wx = w & 1, wy = w >> 1;
  __shared__ unsigned short As[128 * 64];
  __shared__ unsigned short Bs[128 * 64];
  f32x4 acc[4][4];
  f32x4 zero = {0.f, 0.f, 0.f, 0.f};
#pragma unroll
  for (int mi = 0; mi < 4; ++mi)
#pragma unroll
    for (int nj = 0; nj < 4; ++nj) acc[mi][nj] = zero;
  const unsigned short* xg = xaug + (size_t)nb * 1024;
  int lr = lane >> 3, lc = lane & 7;
  int gcs = (lc ^ lr) * 8;
  for (int kt = 0; kt < 4; ++kt) {
    int kof = kq * 256 + kt * 64;
#pragma unroll
    for (int it = 0; it < 4; ++it) {
      int row = w * 8 + it * 32 + lr;
      ldst16(&As[(w * 8 + it * 32) * 64], xg + (size_t)row * 1024 + kof + gcs);
      ldst16(&Bs[(w * 8 + it * 32) * 64], Waug + (size_t)row * 1024 + kof + gcs);
    }
    __syncthreads();
#pragma unroll
    for (int kk = 0; kk < 2; ++kk) {
      int sw = ((kk * 4 + (lane >> 4)) ^ (lane & 7)) * 8;
      short8 av[4], bv[4];
#pragma unroll
      for (int mi = 0; mi < 4; ++mi)
        av[mi] = *reinterpret_cast<const short8*>(&As[(wy * 64 + mi * 16 + (lane & 15)) * 64 + sw]);
#pragma unroll
      for (int nj = 0; nj < 4; ++nj)
        bv[nj] = *reinterpret_cast<const short8*>(&Bs[(wx * 64 + nj * 16 + (lane & 15)) * 64 + sw]);
#pragma unroll
      for (int mi = 0; mi < 4; ++mi)
#pragma unroll
        for (int nj = 0; nj < 4; ++nj)
          acc[mi][nj] = __builtin_amdgcn_mfma_f32_16x16x32_bf16(av[mi], bv[nj], acc[mi][nj], 0, 0, 0);
    }
    __syncthreads();
  }
  float* outp = r12p + (size_t)kq * KC * NN;
#pragma unroll
  for (int mi = 0; mi < 4; ++mi)
#pragma unroll
    for (int nj = 0; nj < 4; ++nj) {
      int ccol = wx * 64 + nj * 16 + (lane & 15);
      int nrow = nb + wy * 64 + mi * 16 + (lane >> 4) * 4;
      float4 o;
      o.x = acc[mi][nj][0]; o.y = acc[mi][nj][1]; o.z = acc[mi][nj][2]; o.w = acc[mi][nj][3];
      *reinterpret_cast<float4*>(&outp[(size_t)ccol * NN + nrow]) = o;
    }
}

// ============ MAIN: x @ Gt^T + fused 0.5||u-h||^2 + c0 + r12 ============
__global__ __launch_bounds__(256) void mfa_main(const unsigned short* __restrict__ xaug,
                                                const unsigned short* __restrict__ Gt,
                                                const float* __restrict__ hws,
                                                const float* __restrict__ c0g,
                                                const float* __restrict__ r12p,
                                                float* __restrict__ s2b) {
  int bx = blockIdx.x, by = blockIdx.y;
  int tid = threadIdx.x, lane = tid & 63, w = tid >> 6, wx = w & 1, wy = w >> 1;
  __shared__ unsigned short As[128 * 64];
  __shared__ unsigned short Bs[128 * 64];
  f32x4 acc[4][4];
  f32x4 zero = {0.f, 0.f, 0.f, 0.f};
#pragma unroll
  for (int mi = 0; mi < 4; ++mi)
#pragma unroll
    for (int nj = 0; nj < 4; ++nj) acc[mi][nj] = zero;
  int nbase = by * 128, cbase = bx * 128;
  const unsigned short* xg = xaug + (size_t)nbase * 1024;
  const unsigned short* gg = Gt + (size_t)cbase * DF;
  int lr = lane >> 3, lc = lane & 7;
  int gcs = (lc ^ lr) * 8;
  for (int kt = 0; kt < 8; ++kt) {
#pragma unroll
    for (int it = 0; it < 4; ++it) {
      int row = w * 8 + it * 32 + lr;
      ldst16(&As[(w * 8 + it * 32) * 64], xg + (size_t)row * 1024 + kt * 64 + gcs);
      ldst16(&Bs[(w * 8 + it * 32) * 64], gg + (size_t)row * DF + kt * 64 + gcs);
    }
    __syncthreads();
#pragma unroll
    for (int kk = 0; kk < 2; ++kk) {
      int sw = ((kk * 4 + (lane >> 4)) ^ (lane & 7)) * 8;
      short8 av[4], bv[4];
#pragma unroll
      for (int mi = 0; mi < 4; ++mi)
        av[mi] = *reinterpret_cast<const short8*>(&As[(wy * 64 + mi * 16 + (lane & 15)) * 64 + sw]);
#pragma unroll
      for (int nj = 0; nj < 4; ++nj)
        bv[nj] = *reinterpret_cast<const short8*>(&Bs[(wx * 64 + nj * 16 + (lane & 15)) * 64 + sw]);
#pragma unroll
      for (int mi = 0; mi < 4; ++mi)
#pragma unroll
        for (int nj = 0; nj < 4; ++nj)
          acc[mi][nj] = __builtin_amdgcn_mfma_f32_16x16x32_bf16(av[mi], bv[nj], acc[mi][nj], 0, 0, 0);
    }
    __syncthreads();
  }
  int comp = bx * 2 + wx;
  float hv[4];
#pragma unroll
  for (int nj = 0; nj < 4; ++nj) hv[nj] = hws[comp * 64 + nj * 16 + (lane & 15)];
  float cc = c0g[comp];
  int rbase = nbase + wy * 64;
#pragma unroll
  for (int mi = 0; mi < 4; ++mi) {
    f32x4 sv;
#pragma unroll
    for (int reg = 0; reg < 4; ++reg) {
      float s = 0.f;
#pragma unroll
      for (int nj = 0; nj < 4; ++nj) {
        float dlt = acc[mi][nj][reg] - hv[nj];
        s += dlt * dlt;
      }
      s += __shfl_xor(s, 1, 64);
      s += __shfl_xor(s, 2, 64);
      s += __shfl_xor(s, 4, 64);
      s += __shfl_xor(s, 8, 64);
      sv[reg] = s;
    }
    if ((lane & 15) == 0) {
      int nr = rbase + mi * 16 + (lane >> 4) * 4;
      size_t idx = (size_t)comp * NN + nr;
      float4 r0 = *reinterpret_cast<const float4*>(&r12p[idx]);
      float4 r1 = *reinterpret_cast<const float4*>(&r12p[(size_t)KC * NN + idx]);
      float4 r2 = *reinterpret_cast<const float4*>(&r12p[(size_t)2 * KC * NN + idx]);
      float4 r3 = *reinterpret_cast<const float4*>(&r12p[(size_t)3 * KC * NN + idx]);
      float4 o;
      o.x = 0.5f * sv[0] + cc + r0.x + r1.x + r2.x + r3.x;
      o.y = 0.5f * sv[1] + cc + r0.y + r1.y + r2.y + r3.y;
      o.z = 0.5f * sv[2] + cc + r0.z + r1.z + r2.z + r3.z;
      o.w = 0.5f * sv[3] + cc + r0.w + r1.w + r2.w + r3.w;
      *reinterpret_cast<float4*>(&s2b[idx]) = o;
    }
  }
}

// ============ LSE over K ============
__global__ __launch_bounds__(64) void mfa_lse(const float* __restrict__ s2b,
                                              float* __restrict__ out) {
  int n = blockIdx.x * 64 + threadIdx.x;
  float m = -3.0e38f, s = 0.f;
#pragma unroll 8
  for (int k = 0; k < KC; ++k) {
    float t = s2b[(size_t)k * NN + n];
    float nm = fmaxf(m, t);
    s = s * expf(m - nm) + expf(t - nm);
    m = nm;
  }
  out[n] = m + logf(s);
}

extern "C" void kernel_launch(void* const* d_in, const int* in_sizes, int n_in,
                              void* d_out, int out_size, void* d_ws, size_t ws_size,
                              hipStream_t stream) {
  const float* x  = (const float*)d_in[0];
  const float* MU = (const float*)d_in[1];
  const float* A  = (const float*)d_in[2];
  const float* Dp = (const float*)d_in[3];
  const float* PI = (const float*)d_in[4];
  float* out = (float*)d_out;

  char* base = (char*)d_ws;
  size_t off = 0;
  auto alloc = [&](size_t bytes) -> void* {
    void* p = base + off;
    off += (bytes + 255) & ~(size_t)255;
    return p;
  };
  unsigned short* xaug = (unsigned short*)alloc((size_t)NN * 1024 * 2);    // 16 MB
  unsigned short* As   = (unsigned short*)alloc((size_t)KC * DF * LF * 2); // 8 MB
  unsigned short* Ast  = (unsigned short*)alloc((size_t)KC * LF * DF * 2); // 8 MB
  unsigned short* Waug = (unsigned short*)alloc((size_t)KC * 1024 * 2);    // 256 KB
  unsigned short* Gt   = (unsigned short*)alloc((size_t)KC * LF * DF * 2); // 8 MB
  float* hws           = (float*)alloc((size_t)KC * 64 * 4);
  float* c0g           = (float*)alloc((size_t)KC * 4);
  float* r12p          = (float*)alloc((size_t)4 * KC * NN * 4);           // 8 MB
  float* s2b           = (float*)alloc((size_t)KC * NN * 4);               // 2 MB

  mfa_prep<<<3072, 256, 0, stream>>>(x, A, Dp, xaug, As, Ast);
  mfa_percomp<<<KC, 256, 0, stream>>>(MU, Dp, PI, Ast, As, Waug, Gt, hws, c0g);
  mfa_q1g<<<dim3(NN / 128, 4), 256, 0, stream>>>(xaug, Waug, r12p);
  mfa_main<<<dim3(64, NN / 128), 256, 0, stream>>>(xaug, Gt, hws, c0g, r12p, s2b);
  mfa_lse<<<NN / 64, 64, 0, stream>>>(s2b, out);
}